// Round 1
// baseline (3414.261 us; speedup 1.0000x reference)
//
#include <hip/hip_runtime.h>

constexpr int H    = 128;
constexpr int LNUM = 5;
constexpr int NG   = 512;
constexpr int EMB  = 640;   // LNUM * H
constexpr float BN_EPS = 1e-5f;

// ---------------- utility ----------------
__global__ void k_zerof(float* p, int n){
  int i = blockIdx.x*256 + threadIdx.x;
  if (i < n) p[i] = 0.f;
}
__global__ void k_zeroi(int* p, int n){
  int i = blockIdx.x*256 + threadIdx.x;
  if (i < n) p[i] = 0;
}

// ---------------- CSR build ----------------
__global__ void k_hist(const int* __restrict__ dst, int E, int* deg){
  int e = blockIdx.x*256 + threadIdx.x;
  if (e < E) atomicAdd(&deg[dst[e]], 1);
}

// degcur: in = degree, out = exclusive prefix (cursor). rowptr gets inclusive at +1.
__global__ __launch_bounds__(1024) void k_scan(int* degcur, int* __restrict__ rowptr, int n){
  __shared__ int sh[1024];
  __shared__ int carry;
  int tid = threadIdx.x;
  if (tid == 0){ carry = 0; rowptr[0] = 0; }
  __syncthreads();
  for (int base = 0; base < n; base += 1024){
    int v = (base + tid < n) ? degcur[base + tid] : 0;
    sh[tid] = v;
    __syncthreads();
    for (int off = 1; off < 1024; off <<= 1){
      int t = (tid >= off) ? sh[tid - off] : 0;
      __syncthreads();
      sh[tid] += t;
      __syncthreads();
    }
    int incl = sh[tid] + carry;
    if (base + tid < n){ rowptr[base + tid + 1] = incl; degcur[base + tid] = incl - v; }
    int tot = sh[1023];
    __syncthreads();
    if (tid == 0) carry += tot;
    __syncthreads();
  }
}

__global__ void k_scatter(const int* __restrict__ src, const int* __restrict__ dst,
                          int E, int* cursor, int* __restrict__ colsrc){
  int e = blockIdx.x*256 + threadIdx.x;
  if (e < E){
    int d = dst[e];
    int pos = atomicAdd(&cursor[d], 1);
    colsrc[pos] = src[e];
  }
}

// graph segment boundaries via binary search on sorted batch
__global__ void k_gstart(const int* __restrict__ batch, int N, int* __restrict__ gstart){
  int g = blockIdx.x*256 + threadIdx.x;
  if (g <= NG){
    int lo = 0, hi = N;
    while (lo < hi){
      int mid = (lo + hi) >> 1;
      if (batch[mid] < g) lo = mid + 1; else hi = mid;
    }
    gstart[g] = lo;
  }
}

// ---------------- GIN aggregation: hpre = (1+eps)*h + sum_{j->n} h[j] ----------------
__global__ __launch_bounds__(128) void k_agg(const float* __restrict__ hin, int ldh,
                                             const int* __restrict__ rowptr,
                                             const int* __restrict__ colsrc,
                                             const float* __restrict__ epsp,
                                             float* __restrict__ out){
  int n = blockIdx.x;
  int t = threadIdx.x;
  float acc = (1.0f + *epsp) * hin[(size_t)n*ldh + t];
  int e0 = rowptr[n], e1 = rowptr[n+1];
  for (int e = e0; e < e1; ++e){
    int s = colsrc[e];
    acc += hin[(size_t)s*ldh + t];
  }
  out[(size_t)n*H + t] = acc;
}

// ---------------- BN stats ----------------
__global__ __launch_bounds__(256) void k_stats(const float* __restrict__ X, int n,
                                               float* sums, float* sumsq){
  int tid = threadIdx.x;
  int c = tid & 127, half = tid >> 7;
  float s = 0.f, q = 0.f;
  for (int r = blockIdx.x*2 + half; r < n; r += gridDim.x*2){
    float v = X[(size_t)r*H + c];
    s += v; q += v*v;
  }
  __shared__ float shs[256], shq[256];
  shs[tid] = s; shq[tid] = q;
  __syncthreads();
  if (tid < 128){
    atomicAdd(&sums[c],  shs[tid] + shs[tid+128]);
    atomicAdd(&sumsq[c], shq[tid] + shq[tid+128]);
  }
}

__global__ void k_bnfin(float* sums, float* sumsq,
                        const float* __restrict__ g, const float* __restrict__ b,
                        float* __restrict__ scale, float* __restrict__ shift, float invn){
  int c = threadIdx.x;
  float m = sums[c]*invn;
  float v = sumsq[c]*invn - m*m;
  float inv = rsqrtf(v + BN_EPS);
  float sc = g[c]*inv;
  scale[c] = sc;
  shift[c] = b[c] - m*sc;
  sums[c] = 0.f; sumsq[c] = 0.f;   // ready for next use
}

// out[r, c] = relu(scale[c]*U[r,c] + shift[c]), out has leading-dim ldo (writes one 128-col block)
__global__ __launch_bounds__(256) void k_bnstore(const float* __restrict__ U,
                                                 const float* __restrict__ scale,
                                                 const float* __restrict__ shift,
                                                 float* __restrict__ out, int ldo, int n){
  int i = blockIdx.x*256 + threadIdx.x;  // one float4 group
  int total = n * (H/4);
  if (i < total){
    int r = i >> 5;
    int c4 = (i & 31) << 2;
    float4 u  = *(const float4*)(U + (size_t)r*H + c4);
    float4 sc = *(const float4*)(scale + c4);
    float4 sf = *(const float4*)(shift + c4);
    float4 o;
    o.x = fmaxf(fmaf(sc.x, u.x, sf.x), 0.f);
    o.y = fmaxf(fmaf(sc.y, u.y, sf.y), 0.f);
    o.z = fmaxf(fmaf(sc.z, u.z, sf.z), 0.f);
    o.w = fmaxf(fmaf(sc.w, u.w, sf.w), 0.f);
    *(float4*)(out + (size_t)r*ldo + c4) = o;
  }
}

// ---------------- pooling + prediction heads ----------------
__global__ __launch_bounds__(640) void k_pool(const float* __restrict__ xall,
                                              const int* __restrict__ gstart,
                                              float* __restrict__ pooled){
  int g = blockIdx.x;
  int t = threadIdx.x;
  int n0 = gstart[g], n1 = gstart[g+1];
  float acc = 0.f;
  for (int n = n0; n < n1; ++n) acc += xall[(size_t)n*EMB + t];
  pooled[(size_t)g*EMB + t] = acc;
}

__global__ __launch_bounds__(128) void k_pred(const float* __restrict__ pooled,
                                              const float* __restrict__ W,
                                              const float* __restrict__ b,
                                              float* __restrict__ xcat){
  int g = blockIdx.x, l = blockIdx.y, o = threadIdx.x;
  __shared__ float sh[128];
  sh[o] = pooled[(size_t)g*EMB + l*H + o];
  __syncthreads();
  const float* Wl = W + (size_t)l*H*H;
  float acc = b[l*H + o];
  for (int k = 0; k < H; ++k) acc = fmaf(sh[k], Wl[k*H + o], acc);
  xcat[(size_t)g*EMB + l*H + o] = acc;
}

// ---------------- f32 GEMM, 128x128 tile, 256 thr, 8x8/thread ----------------
// C = epilogue(A' @ B + bias), A' = PRO_BN ? relu(kscale[k]*A + kshift[k]) : A
template<bool PRO_BN, bool RELU, bool ADD_D>
__global__ __launch_bounds__(256) void k_gemm128(
    const float* __restrict__ A, int lda,
    const float* __restrict__ B, int ldb,
    const float* __restrict__ bias,
    const float* __restrict__ kscale, const float* __restrict__ kshift,
    const float* D, int ldd,
    float* C, int ldc,
    int M, int N, int K)
{
  __shared__ float As[32][132];   // k-major, padded
  __shared__ float Bs[32][128];
  const int tid  = threadIdx.x;
  const int tx   = tid & 15;
  const int ty   = tid >> 4;
  const int row0 = blockIdx.x * 128;
  const int col0 = blockIdx.y * 128;
  const int am = tid >> 3;
  const int ak = (tid & 7) << 2;
  const int bk = tid >> 5;
  const int bn = (tid & 31) << 2;
  float acc[8][8] = {};

  for (int k0 = 0; k0 < K; k0 += 32){
#pragma unroll
    for (int h = 0; h < 4; ++h){
      int m  = am + h*32;
      int gr = row0 + m;
      float4 v = make_float4(0.f, 0.f, 0.f, 0.f);
      if (gr < M) v = *(const float4*)(A + (size_t)gr*lda + k0 + ak);
      if (PRO_BN){
        float4 sc = *(const float4*)(kscale + k0 + ak);
        float4 sf = *(const float4*)(kshift + k0 + ak);
        v.x = fmaxf(fmaf(sc.x, v.x, sf.x), 0.f);
        v.y = fmaxf(fmaf(sc.y, v.y, sf.y), 0.f);
        v.z = fmaxf(fmaf(sc.z, v.z, sf.z), 0.f);
        v.w = fmaxf(fmaf(sc.w, v.w, sf.w), 0.f);
      }
      As[ak+0][m] = v.x; As[ak+1][m] = v.y; As[ak+2][m] = v.z; As[ak+3][m] = v.w;
    }
#pragma unroll
    for (int h = 0; h < 4; ++h){
      int kk = bk + h*8;
      *(float4*)(&Bs[kk][bn]) = *(const float4*)(B + (size_t)(k0+kk)*ldb + col0 + bn);
    }
    __syncthreads();
#pragma unroll 4
    for (int k = 0; k < 32; ++k){
      float4 a0 = *(const float4*)(&As[k][ty<<3]);
      float4 a1 = *(const float4*)(&As[k][(ty<<3) + 4]);
      float4 b0 = *(const float4*)(&Bs[k][tx<<3]);
      float4 b1 = *(const float4*)(&Bs[k][(tx<<3) + 4]);
      float av[8] = {a0.x,a0.y,a0.z,a0.w,a1.x,a1.y,a1.z,a1.w};
      float bv[8] = {b0.x,b0.y,b0.z,b0.w,b1.x,b1.y,b1.z,b1.w};
#pragma unroll
      for (int i = 0; i < 8; ++i)
#pragma unroll
        for (int j = 0; j < 8; ++j)
          acc[i][j] = fmaf(av[i], bv[j], acc[i][j]);
    }
    __syncthreads();
  }

  const int col = col0 + (tx<<3);
  float4 bv0 = *(const float4*)(bias + col);
  float4 bv1 = *(const float4*)(bias + col + 4);
#pragma unroll
  for (int i = 0; i < 8; ++i){
    int row = row0 + (ty<<3) + i;
    if (row < M){
      float r[8];
      r[0]=acc[i][0]+bv0.x; r[1]=acc[i][1]+bv0.y; r[2]=acc[i][2]+bv0.z; r[3]=acc[i][3]+bv0.w;
      r[4]=acc[i][4]+bv1.x; r[5]=acc[i][5]+bv1.y; r[6]=acc[i][6]+bv1.z; r[7]=acc[i][7]+bv1.w;
      if (RELU){
#pragma unroll
        for (int j = 0; j < 8; ++j) r[j] = fmaxf(r[j], 0.f);
      }
      if (ADD_D){
        float4 d0 = *(const float4*)(D + (size_t)row*ldd + col);
        float4 d1 = *(const float4*)(D + (size_t)row*ldd + col + 4);
        r[0]+=d0.x; r[1]+=d0.y; r[2]+=d0.z; r[3]+=d0.w;
        r[4]+=d1.x; r[5]+=d1.y; r[6]+=d1.z; r[7]+=d1.w;
      }
      *(float4*)(C + (size_t)row*ldc + col)     = make_float4(r[0],r[1],r[2],r[3]);
      *(float4*)(C + (size_t)row*ldc + col + 4) = make_float4(r[4],r[5],r[6],r[7]);
    }
  }
}

// ---------------- f32 GEMM, 64x64 tile, 256 thr, 4x4/thread (small M) ----------------
template<bool RELU, bool ADD_D>
__global__ __launch_bounds__(256) void k_gemm64(
    const float* __restrict__ A, int lda,
    const float* __restrict__ B, int ldb,
    const float* __restrict__ bias,
    const float* D, int ldd,
    float* C, int ldc,
    int M, int N, int K)
{
  __shared__ float As[32][68];
  __shared__ float Bs[32][64];
  const int tid  = threadIdx.x;
  const int tx   = tid & 15;
  const int ty   = tid >> 4;
  const int row0 = blockIdx.x * 64;
  const int col0 = blockIdx.y * 64;
  const int am = tid >> 3;
  const int ak = (tid & 7) << 2;
  const int bk = tid >> 4;
  const int bn = (tid & 15) << 2;
  float acc[4][4] = {};

  for (int k0 = 0; k0 < K; k0 += 32){
#pragma unroll
    for (int h = 0; h < 2; ++h){
      int m  = am + h*32;
      int gr = row0 + m;
      float4 v = make_float4(0.f, 0.f, 0.f, 0.f);
      if (gr < M) v = *(const float4*)(A + (size_t)gr*lda + k0 + ak);
      As[ak+0][m]=v.x; As[ak+1][m]=v.y; As[ak+2][m]=v.z; As[ak+3][m]=v.w;
    }
#pragma unroll
    for (int h = 0; h < 2; ++h){
      int kk = bk + h*16;
      *(float4*)(&Bs[kk][bn]) = *(const float4*)(B + (size_t)(k0+kk)*ldb + col0 + bn);
    }
    __syncthreads();
#pragma unroll 8
    for (int k = 0; k < 32; ++k){
      float4 a = *(const float4*)(&As[k][ty<<2]);
      float4 b = *(const float4*)(&Bs[k][tx<<2]);
      float av[4] = {a.x,a.y,a.z,a.w};
      float bv[4] = {b.x,b.y,b.z,b.w};
#pragma unroll
      for (int i = 0; i < 4; ++i)
#pragma unroll
        for (int j = 0; j < 4; ++j)
          acc[i][j] = fmaf(av[i], bv[j], acc[i][j]);
    }
    __syncthreads();
  }

  const int col = col0 + (tx<<2);
  float4 bv = *(const float4*)(bias + col);
#pragma unroll
  for (int i = 0; i < 4; ++i){
    int row = row0 + (ty<<2) + i;
    if (row < M){
      float r[4] = {acc[i][0]+bv.x, acc[i][1]+bv.y, acc[i][2]+bv.z, acc[i][3]+bv.w};
      if (RELU){
#pragma unroll
        for (int j = 0; j < 4; ++j) r[j] = fmaxf(r[j], 0.f);
      }
      if (ADD_D){
        float4 d = *(const float4*)(D + (size_t)row*ldd + col);
        r[0]+=d.x; r[1]+=d.y; r[2]+=d.z; r[3]+=d.w;
      }
      *(float4*)(C + (size_t)row*ldc + col) = make_float4(r[0],r[1],r[2],r[3]);
    }
  }
}

// ---------------- host ----------------
extern "C" void kernel_launch(void* const* d_in, const int* in_sizes, int n_in,
                              void* d_out, int out_size, void* d_ws, size_t ws_size,
                              hipStream_t stream) {
  const float* x        = (const float*)d_in[0];
  const int*   ei       = (const int*)d_in[1];
  const int*   batch    = (const int*)d_in[2];
  const float* conv_W1  = (const float*)d_in[3];
  const float* conv_b1  = (const float*)d_in[4];
  const float* conv_g1  = (const float*)d_in[5];
  const float* conv_be1 = (const float*)d_in[6];
  const float* conv_W2  = (const float*)d_in[7];
  const float* conv_b2  = (const float*)d_in[8];
  const float* epsv     = (const float*)d_in[9];
  const float* bn_g     = (const float*)d_in[10];
  const float* bn_b     = (const float*)d_in[11];
  const float* pred_W   = (const float*)d_in[12];
  const float* pred_b   = (const float*)d_in[13];
  const float* gW       = (const float*)d_in[14];
  const float* gb       = (const float*)d_in[15];
  const float* gsW      = (const float*)d_in[16];
  const float* gsb      = (const float*)d_in[17];
  const float* lW       = (const float*)d_in[18];
  const float* lb       = (const float*)d_in[19];
  const float* lsW      = (const float*)d_in[20];
  const float* lsb      = (const float*)d_in[21];

  const int N = in_sizes[0] / H;
  const int E = in_sizes[1] / 2;
  const int* srcI = ei;
  const int* dstI = ei + E;

  float* out = (float*)d_out;
  float* GE = out;                              // [NG][EMB]
  float* NE = out + (size_t)NG*EMB;             // [N][EMB]
  float* XC = NE + (size_t)N*EMB;               // [NG][EMB]

  float* ws      = (float*)d_ws;
  float* xall    = ws;                          // [N][EMB]
  float* tmpA    = xall + (size_t)N*EMB;        // [N][EMB]
  float* pooled  = tmpA + (size_t)N*EMB;        // [NG][EMB]
  float* gtmp1   = pooled + (size_t)NG*EMB;
  float* gtmp2   = gtmp1 + (size_t)NG*EMB;
  float* sums    = gtmp2 + (size_t)NG*EMB;      // [128]
  float* sumsq   = sums + 128;
  float* bnscale = sumsq + 128;
  float* bnshift = bnscale + 128;
  int*   rowptr  = (int*)(bnshift + 128);       // [N+1]
  int*   cursor  = rowptr + (N + 1);            // [N]
  int*   colsrc  = cursor + N;                  // [E]
  int*   gstart  = colsrc + E;                  // [NG+1]

  float* hpre = tmpA;                           // [N][H]  (carved from tmpA)
  float* tbuf = tmpA + (size_t)N*H;             // [N][H]
  float* ubuf = tmpA + (size_t)2*N*H;           // [N][H]

  // stat accumulators must be zero every call (ws is poisoned once, never re-poisoned)
  k_zerof<<<1, 256, 0, stream>>>(sums, 256);

  // CSR build
  k_zeroi<<<(N+255)/256, 256, 0, stream>>>(cursor, N);
  k_hist<<<(E+255)/256, 256, 0, stream>>>(dstI, E, cursor);
  k_scan<<<1, 1024, 0, stream>>>(cursor, rowptr, N);
  k_scatter<<<(E+255)/256, 256, 0, stream>>>(srcI, dstI, E, cursor, colsrc);
  k_gstart<<<(NG+256)/256, 256, 0, stream>>>(batch, N, gstart);

  const float invn = 1.0f / (float)N;
  const dim3 gconv((N + 127)/128, H/128);       // (391, 1)

  for (int l = 0; l < LNUM; ++l){
    const float* hin = (l == 0) ? x : (xall + (size_t)(l-1)*H);
    const int ldh    = (l == 0) ? H : EMB;
    k_agg<<<N, 128, 0, stream>>>(hin, ldh, rowptr, colsrc, epsv + l, hpre);

    k_gemm128<false,false,false><<<gconv, 256, 0, stream>>>(
        hpre, H, conv_W1 + (size_t)l*H*H, H, conv_b1 + l*H,
        nullptr, nullptr, nullptr, 0, tbuf, H, N, H, H);
    k_stats<<<512, 256, 0, stream>>>(tbuf, N, sums, sumsq);
    k_bnfin<<<1, 128, 0, stream>>>(sums, sumsq, conv_g1 + l*H, conv_be1 + l*H,
                                   bnscale, bnshift, invn);
    k_gemm128<true,false,false><<<gconv, 256, 0, stream>>>(
        tbuf, H, conv_W2 + (size_t)l*H*H, H, conv_b2 + l*H,
        bnscale, bnshift, nullptr, 0, ubuf, H, N, H, H);
    k_stats<<<512, 256, 0, stream>>>(ubuf, N, sums, sumsq);
    k_bnfin<<<1, 128, 0, stream>>>(sums, sumsq, bn_g + l*H, bn_b + l*H,
                                   bnscale, bnshift, invn);
    k_bnstore<<<((size_t)N*32 + 255)/256, 256, 0, stream>>>(
        ubuf, bnscale, bnshift, xall + (size_t)l*H, EMB, N);
  }

  // pooling + per-layer prediction heads -> xcat (third output)
  k_pool<<<NG, EMB, 0, stream>>>(xall, gstart, pooled);
  k_pred<<<dim3(NG, LNUM), 128, 0, stream>>>(pooled, pred_W, pred_b, XC);

  // graph FF: GE = relu-chain(XC) + XC @ gsW + gsb
  const dim3 gg((NG + 63)/64, EMB/64);          // (8, 10)
  k_gemm64<false,false><<<gg, 256, 0, stream>>>(XC, EMB, gsW, EMB, gsb,
                                                nullptr, 0, GE, EMB, NG, EMB, EMB);
  k_gemm64<true,false><<<gg, 256, 0, stream>>>(XC, EMB, gW, EMB, gb,
                                               nullptr, 0, gtmp1, EMB, NG, EMB, EMB);
  k_gemm64<true,false><<<gg, 256, 0, stream>>>(gtmp1, EMB, gW + (size_t)EMB*EMB, EMB, gb + EMB,
                                               nullptr, 0, gtmp2, EMB, NG, EMB, EMB);
  k_gemm64<true,true><<<gg, 256, 0, stream>>>(gtmp2, EMB, gW + (size_t)2*EMB*EMB, EMB, gb + 2*EMB,
                                              GE, EMB, GE, EMB, NG, EMB, EMB);

  // node FF: NE = relu-chain(xall) + xall @ lsW + lsb
  const dim3 gn((N + 127)/128, EMB/128);        // (391, 5)
  k_gemm128<false,false,false><<<gn, 256, 0, stream>>>(
      xall, EMB, lsW, EMB, lsb, nullptr, nullptr, nullptr, 0, NE, EMB, N, EMB, EMB);
  k_gemm128<false,true,false><<<gn, 256, 0, stream>>>(
      xall, EMB, lW, EMB, lb, nullptr, nullptr, nullptr, 0, tmpA, EMB, N, EMB, EMB);
  k_gemm128<false,true,false><<<gn, 256, 0, stream>>>(
      tmpA, EMB, lW + (size_t)EMB*EMB, EMB, lb + EMB,
      nullptr, nullptr, nullptr, 0, xall, EMB, N, EMB, EMB);
  k_gemm128<false,true,true><<<gn, 256, 0, stream>>>(
      xall, EMB, lW + (size_t)2*EMB*EMB, EMB, lb + 2*EMB,
      nullptr, nullptr, NE, EMB, NE, EMB, N, EMB, EMB);
}

// Round 2
// 1816.235 us; speedup vs baseline: 1.8799x; 1.8799x over previous
//
#include <hip/hip_runtime.h>

constexpr int H    = 128;
constexpr int LNUM = 5;
constexpr int NG   = 512;
constexpr int EMB  = 640;   // LNUM * H
constexpr float BN_EPS = 1e-5f;

typedef __attribute__((ext_vector_type(8))) short bf16x8;
typedef __attribute__((ext_vector_type(4))) float f32x4;

__device__ inline unsigned short f2bf(float f){
  unsigned u = __builtin_bit_cast(unsigned, f);
  u += 0x7FFF + ((u >> 16) & 1);
  return (unsigned short)(u >> 16);
}
__device__ inline float bf2f(unsigned short h){
  unsigned u = ((unsigned)h) << 16;
  return __builtin_bit_cast(float, u);
}

// ---------------- utility ----------------
__global__ void k_zerof(float* p, int n){
  int i = blockIdx.x*256 + threadIdx.x;
  if (i < n) p[i] = 0.f;
}
__global__ void k_zeroi(int* p, int n){
  int i = blockIdx.x*256 + threadIdx.x;
  if (i < n) p[i] = 0;
}

// ---------------- CSR build ----------------
__global__ void k_hist(const int* __restrict__ dst, int E, int* deg){
  int e = blockIdx.x*256 + threadIdx.x;
  if (e < E) atomicAdd(&deg[dst[e]], 1);
}

__global__ __launch_bounds__(1024) void k_scan(int* degcur, int* __restrict__ rowptr, int n){
  __shared__ int sh[1024];
  __shared__ int carry;
  int tid = threadIdx.x;
  if (tid == 0){ carry = 0; rowptr[0] = 0; }
  __syncthreads();
  for (int base = 0; base < n; base += 1024){
    int v = (base + tid < n) ? degcur[base + tid] : 0;
    sh[tid] = v;
    __syncthreads();
    for (int off = 1; off < 1024; off <<= 1){
      int t = (tid >= off) ? sh[tid - off] : 0;
      __syncthreads();
      sh[tid] += t;
      __syncthreads();
    }
    int incl = sh[tid] + carry;
    if (base + tid < n){ rowptr[base + tid + 1] = incl; degcur[base + tid] = incl - v; }
    int tot = sh[1023];
    __syncthreads();
    if (tid == 0) carry += tot;
    __syncthreads();
  }
}

__global__ void k_scatter(const int* __restrict__ src, const int* __restrict__ dst,
                          int E, int* cursor, int* __restrict__ colsrc){
  int e = blockIdx.x*256 + threadIdx.x;
  if (e < E){
    int d = dst[e];
    int pos = atomicAdd(&cursor[d], 1);
    colsrc[pos] = src[e];
  }
}

__global__ void k_gstart(const int* __restrict__ batch, int N, int* __restrict__ gstart){
  int g = blockIdx.x*256 + threadIdx.x;
  if (g <= NG){
    int lo = 0, hi = N;
    while (lo < hi){
      int mid = (lo + hi) >> 1;
      if (batch[mid] < g) lo = mid + 1; else hi = mid;
    }
    gstart[g] = lo;
  }
}

// ---------------- weight cast+transpose: W[k][n] f32 -> Wt[n][k] bf16 ----------------
__global__ void k_castT(const float* __restrict__ W, unsigned short* __restrict__ Wt,
                        int K, int N){
  __shared__ float sh[32][33];
  const size_t moff = (size_t)blockIdx.z * K * N;
  int n0 = blockIdx.x*32, k0 = blockIdx.y*32;
  int tx = threadIdx.x, ty = threadIdx.y;   // 32 x 8
  for (int r = ty; r < 32; r += 8)
    sh[r][tx] = W[moff + (size_t)(k0 + r)*N + n0 + tx];
  __syncthreads();
  for (int r = ty; r < 32; r += 8)
    Wt[moff + (size_t)(n0 + r)*K + k0 + tx] = f2bf(sh[tx][r]);
}

// ---------------- GIN aggregation: out = bf16((1+eps)*h + sum_{j->n} h[j]) ----------------
template<bool IN_BF16>
__global__ __launch_bounds__(128) void k_agg(const void* __restrict__ hin_, int ldh,
                                             const int* __restrict__ rowptr,
                                             const int* __restrict__ colsrc,
                                             const float* __restrict__ epsp,
                                             unsigned short* __restrict__ out){
  int n = blockIdx.x;
  int t = threadIdx.x;
  float self;
  if (IN_BF16) self = bf2f(((const unsigned short*)hin_)[(size_t)n*ldh + t]);
  else         self = ((const float*)hin_)[(size_t)n*ldh + t];
  float acc = (1.0f + *epsp) * self;
  int e0 = rowptr[n], e1 = rowptr[n+1];
  for (int e = e0; e < e1; ++e){
    int s = colsrc[e];
    if (IN_BF16) acc += bf2f(((const unsigned short*)hin_)[(size_t)s*ldh + t]);
    else         acc += ((const float*)hin_)[(size_t)s*ldh + t];
  }
  out[(size_t)n*H + t] = f2bf(acc);
}

// ---------------- BN stats (f32 input [n][128]) ----------------
__global__ __launch_bounds__(256) void k_stats(const float* __restrict__ X, int n,
                                               float* sums, float* sumsq){
  int tid = threadIdx.x;
  int c = tid & 127, half = tid >> 7;
  float s = 0.f, q = 0.f;
  for (int r = blockIdx.x*2 + half; r < n; r += gridDim.x*2){
    float v = X[(size_t)r*H + c];
    s += v; q += v*v;
  }
  __shared__ float shs[256], shq[256];
  shs[tid] = s; shq[tid] = q;
  __syncthreads();
  if (tid < 128){
    atomicAdd(&sums[c],  shs[tid] + shs[tid+128]);
    atomicAdd(&sumsq[c], shq[tid] + shq[tid+128]);
  }
}

__global__ void k_bnfin(float* sums, float* sumsq,
                        const float* __restrict__ g, const float* __restrict__ b,
                        float* __restrict__ scale, float* __restrict__ shift, float invn){
  int c = threadIdx.x;
  float m = sums[c]*invn;
  float v = sumsq[c]*invn - m*m;
  float inv = rsqrtf(v + BN_EPS);
  float sc = g[c]*inv;
  scale[c] = sc;
  shift[c] = b[c] - m*sc;
  sums[c] = 0.f; sumsq[c] = 0.f;
}

// out[r][c] = bf16(relu(scale[c]*U[r][c] + shift[c])), out leading-dim ldo
__global__ __launch_bounds__(256) void k_bnapply(const float* __restrict__ U,
                                                 const float* __restrict__ scale,
                                                 const float* __restrict__ shift,
                                                 unsigned short* __restrict__ out,
                                                 int ldo, int n){
  int i = blockIdx.x*256 + threadIdx.x;
  int total = n * (H/4);
  if (i < total){
    int r = i >> 5;
    int c4 = (i & 31) << 2;
    float4 uv = *(const float4*)(U + (size_t)r*H + c4);
    float4 sc = *(const float4*)(scale + c4);
    float4 sf = *(const float4*)(shift + c4);
    float a = fmaxf(fmaf(sc.x, uv.x, sf.x), 0.f);
    float b = fmaxf(fmaf(sc.y, uv.y, sf.y), 0.f);
    float c = fmaxf(fmaf(sc.z, uv.z, sf.z), 0.f);
    float d = fmaxf(fmaf(sc.w, uv.w, sf.w), 0.f);
    uint2 o;
    o.x = (unsigned)f2bf(a) | ((unsigned)f2bf(b) << 16);
    o.y = (unsigned)f2bf(c) | ((unsigned)f2bf(d) << 16);
    *(uint2*)(out + (size_t)r*ldo + c4) = o;
  }
}

// ---------------- pooling + prediction heads ----------------
__global__ __launch_bounds__(640) void k_pool(const unsigned short* __restrict__ xall,
                                              const int* __restrict__ gstart,
                                              float* __restrict__ pooled){
  int g = blockIdx.x;
  int t = threadIdx.x;
  int n0 = gstart[g], n1 = gstart[g+1];
  float acc = 0.f;
  for (int n = n0; n < n1; ++n) acc += bf2f(xall[(size_t)n*EMB + t]);
  pooled[(size_t)g*EMB + t] = acc;
}

__global__ __launch_bounds__(128) void k_pred(const float* __restrict__ pooled,
                                              const float* __restrict__ W,
                                              const float* __restrict__ b,
                                              float* __restrict__ xcat){
  int g = blockIdx.x, l = blockIdx.y, o = threadIdx.x;
  __shared__ float sh[128];
  sh[o] = pooled[(size_t)g*EMB + l*H + o];
  __syncthreads();
  const float* Wl = W + (size_t)l*H*H;
  float acc = b[l*H + o];
  for (int k = 0; k < H; ++k) acc = fmaf(sh[k], Wl[k*H + o], acc);
  xcat[(size_t)g*EMB + l*H + o] = acc;
}

// ---------------- bf16 MFMA GEMM: C = epi(A[M][K] @ Bt[N][K]^T + bias) ----------------
// 128x128 tile, BK=64, 4 waves (2x2), 16x16x32 MFMA, XOR-swizzled LDS via
// pre-swizzled global_load_lds sources (rule 21: linear dest + inv-swz source + swz read).
template<bool RELU, bool ADD_D, bool OUT_BF16>
__global__ __launch_bounds__(256) void k_mm(
    const unsigned short* __restrict__ A, int lda,
    const unsigned short* __restrict__ Bt, int ldb,
    const float* __restrict__ bias,
    const float* __restrict__ D, int ldd,
    void* __restrict__ Cv, int ldc,
    int M, int K)
{
  __shared__ unsigned short As[128*64];   // 16 KB, rows=m, 128B per row (64 bf16)
  __shared__ unsigned short Bs[128*64];   // 16 KB, rows=n
  const int tid  = threadIdx.x;
  const int lane = tid & 63;
  const int w    = tid >> 6;
  const int wr   = w >> 1, wc = w & 1;
  const int row0 = blockIdx.x * 128;
  const int col0 = blockIdx.y * 128;

  // staging: wave w owns LDS bytes [w*4K, w*4K+4K) of each tile; 4 chunks of 1KB
  const unsigned short* sA[4];
  const unsigned short* sB[4];
#pragma unroll
  for (int j = 0; j < 4; ++j){
    int d = w*4096 + j*1024 + lane*16;        // linear LDS byte dest
    int m = d >> 7;                           // tile row this dest belongs to
    int inner = (d & 127) ^ ((m & 7) << 4);   // inverse-swizzled byte-in-row
    int gm = row0 + m; if (gm > M-1) gm = M-1;
    sA[j] = A  + (size_t)gm*lda + (inner >> 1);
    sB[j] = Bt + (size_t)(col0 + m)*ldb + (inner >> 1);
  }

  f32x4 acc[4][4];
#pragma unroll
  for (int i = 0; i < 4; ++i)
#pragma unroll
    for (int j = 0; j < 4; ++j)
      acc[i][j] = (f32x4){0.f, 0.f, 0.f, 0.f};

  for (int k0 = 0; k0 < K; k0 += 64){
#pragma unroll
    for (int j = 0; j < 4; ++j)
      __builtin_amdgcn_global_load_lds(
          (const __attribute__((address_space(1))) void*)(sA[j] + k0),
          (__attribute__((address_space(3))) void*)((char*)As + w*4096 + j*1024),
          16, 0, 0);
#pragma unroll
    for (int j = 0; j < 4; ++j)
      __builtin_amdgcn_global_load_lds(
          (const __attribute__((address_space(1))) void*)(sB[j] + k0),
          (__attribute__((address_space(3))) void*)((char*)Bs + w*4096 + j*1024),
          16, 0, 0);
    __syncthreads();

#pragma unroll
    for (int kk = 0; kk < 2; ++kk){
      const int kb = kk*64 + ((lane >> 4) << 4);   // byte offset of this lane's k-chunk
      bf16x8 af[4], bfr[4];
#pragma unroll
      for (int i = 0; i < 4; ++i){
        int row  = wr*64 + i*16 + (lane & 15);
        int ab   = (row*128 + kb) ^ ((row & 7) << 4);
        af[i] = *(const bf16x8*)((const char*)As + ab);
        int col  = wc*64 + i*16 + (lane & 15);
        int bb   = (col*128 + kb) ^ ((col & 7) << 4);
        bfr[i] = *(const bf16x8*)((const char*)Bs + bb);
      }
#pragma unroll
      for (int i = 0; i < 4; ++i)
#pragma unroll
        for (int j = 0; j < 4; ++j)
          acc[i][j] = __builtin_amdgcn_mfma_f32_16x16x32_bf16(af[i], bfr[j], acc[i][j], 0, 0, 0);
    }
    __syncthreads();
  }

  float* Cf = (float*)Cv;
  unsigned short* Cb = (unsigned short*)Cv;
#pragma unroll
  for (int j = 0; j < 4; ++j){
    int col = col0 + wc*64 + j*16 + (lane & 15);
    float bs = bias[col];
#pragma unroll
    for (int i = 0; i < 4; ++i){
      int rb = row0 + wr*64 + i*16 + ((lane >> 4) << 2);
#pragma unroll
      for (int r = 0; r < 4; ++r){
        int row = rb + r;
        if (row < M){
          float v = acc[i][j][r] + bs;
          if (RELU) v = fmaxf(v, 0.f);
          if (ADD_D) v += D[(size_t)row*ldd + col];
          if (OUT_BF16) Cb[(size_t)row*ldc + col] = f2bf(v);
          else          Cf[(size_t)row*ldc + col] = v;
        }
      }
    }
  }
}

// ---------------- f32 GEMM 64x64 (graph FF, M=512) ----------------
template<bool RELU, bool ADD_D>
__global__ __launch_bounds__(256) void k_gemm64(
    const float* __restrict__ A, int lda,
    const float* __restrict__ B, int ldb,
    const float* __restrict__ bias,
    const float* D, int ldd,
    float* C, int ldc,
    int M, int N, int K)
{
  __shared__ float As[32][68];
  __shared__ float Bs[32][64];
  const int tid  = threadIdx.x;
  const int tx   = tid & 15;
  const int ty   = tid >> 4;
  const int row0 = blockIdx.x * 64;
  const int col0 = blockIdx.y * 64;
  const int am = tid >> 3;
  const int ak = (tid & 7) << 2;
  const int bk = tid >> 4;
  const int bn = (tid & 15) << 2;
  float acc[4][4] = {};

  for (int k0 = 0; k0 < K; k0 += 32){
#pragma unroll
    for (int h = 0; h < 2; ++h){
      int m  = am + h*32;
      int gr = row0 + m;
      float4 v = make_float4(0.f, 0.f, 0.f, 0.f);
      if (gr < M) v = *(const float4*)(A + (size_t)gr*lda + k0 + ak);
      As[ak+0][m]=v.x; As[ak+1][m]=v.y; As[ak+2][m]=v.z; As[ak+3][m]=v.w;
    }
#pragma unroll
    for (int h = 0; h < 2; ++h){
      int kk = bk + h*16;
      *(float4*)(&Bs[kk][bn]) = *(const float4*)(B + (size_t)(k0+kk)*ldb + col0 + bn);
    }
    __syncthreads();
#pragma unroll 8
    for (int k = 0; k < 32; ++k){
      float4 a = *(const float4*)(&As[k][ty<<2]);
      float4 b = *(const float4*)(&Bs[k][tx<<2]);
      float av[4] = {a.x,a.y,a.z,a.w};
      float bv[4] = {b.x,b.y,b.z,b.w};
#pragma unroll
      for (int i = 0; i < 4; ++i)
#pragma unroll
        for (int j = 0; j < 4; ++j)
          acc[i][j] = fmaf(av[i], bv[j], acc[i][j]);
    }
    __syncthreads();
  }

  const int col = col0 + (tx<<2);
  float4 bv = *(const float4*)(bias + col);
#pragma unroll
  for (int i = 0; i < 4; ++i){
    int row = row0 + (ty<<2) + i;
    if (row < M){
      float r[4] = {acc[i][0]+bv.x, acc[i][1]+bv.y, acc[i][2]+bv.z, acc[i][3]+bv.w};
      if (RELU){
#pragma unroll
        for (int j = 0; j < 4; ++j) r[j] = fmaxf(r[j], 0.f);
      }
      if (ADD_D){
        float4 d = *(const float4*)(D + (size_t)row*ldd + col);
        r[0]+=d.x; r[1]+=d.y; r[2]+=d.z; r[3]+=d.w;
      }
      *(float4*)(C + (size_t)row*ldc + col) = make_float4(r[0],r[1],r[2],r[3]);
    }
  }
}

// ---------------- host ----------------
extern "C" void kernel_launch(void* const* d_in, const int* in_sizes, int n_in,
                              void* d_out, int out_size, void* d_ws, size_t ws_size,
                              hipStream_t stream) {
  const float* x        = (const float*)d_in[0];
  const int*   ei       = (const int*)d_in[1];
  const int*   batch    = (const int*)d_in[2];
  const float* conv_W1  = (const float*)d_in[3];
  const float* conv_b1  = (const float*)d_in[4];
  const float* conv_g1  = (const float*)d_in[5];
  const float* conv_be1 = (const float*)d_in[6];
  const float* conv_W2  = (const float*)d_in[7];
  const float* conv_b2  = (const float*)d_in[8];
  const float* epsv     = (const float*)d_in[9];
  const float* bn_g     = (const float*)d_in[10];
  const float* bn_b     = (const float*)d_in[11];
  const float* pred_W   = (const float*)d_in[12];
  const float* pred_b   = (const float*)d_in[13];
  const float* gW       = (const float*)d_in[14];
  const float* gb       = (const float*)d_in[15];
  const float* gsW      = (const float*)d_in[16];
  const float* gsb      = (const float*)d_in[17];
  const float* lW       = (const float*)d_in[18];
  const float* lb       = (const float*)d_in[19];
  const float* lsW      = (const float*)d_in[20];
  const float* lsb      = (const float*)d_in[21];

  const int N = in_sizes[0] / H;
  const int E = in_sizes[1] / 2;
  const int* srcI = ei;
  const int* dstI = ei + E;

  float* out = (float*)d_out;
  float* GE = out;                              // [NG][EMB]
  float* NE = out + (size_t)NG*EMB;             // [N][EMB]
  float* XC = NE + (size_t)N*EMB;               // [NG][EMB]

  // ---- workspace layout (floats) ----
  float* ws = (float*)d_ws;
  unsigned short* xall = (unsigned short*)ws;               // [N][EMB] bf16
  float* convscr = ws + (size_t)N*EMB/2;                    // 3*N*H floats, reused as h1
  float* tbuf = convscr;                                    // [N][H] f32
  float* ubuf = tbuf + (size_t)N*H;                         // [N][H] f32
  unsigned short* hpre = (unsigned short*)(ubuf + (size_t)N*H);  // [N][H] bf16
  unsigned short* tb16 = hpre + (size_t)N*H;                // [N][H] bf16
  unsigned short* h1 = (unsigned short*)convscr;            // [N][EMB] bf16 (alias, post-conv)
  unsigned short* h2 = (unsigned short*)(ws + (size_t)N*EMB/2 + (size_t)3*N*H); // [N][EMB] bf16
  float* pooled  = ws + (size_t)N*EMB/2 + (size_t)3*N*H + (size_t)N*EMB/2;
  float* gtmp1   = pooled + (size_t)NG*EMB;
  float* gtmp2   = gtmp1 + (size_t)NG*EMB;
  float* sums    = gtmp2 + (size_t)NG*EMB;      // [128]
  float* sumsq   = sums + 128;
  float* bnscale = sumsq + 128;
  float* bnshift = bnscale + 128;
  unsigned short* W1t  = (unsigned short*)(bnshift + 128);  // [L][H][H] bf16 (n-major)
  unsigned short* W2t  = W1t + (size_t)LNUM*H*H;
  unsigned short* lWt  = W2t + (size_t)LNUM*H*H;            // [3][EMB][EMB] bf16
  unsigned short* lsWt = lWt + (size_t)3*EMB*EMB;           // [EMB][EMB] bf16
  int* rowptr = (int*)(lsWt + (size_t)EMB*EMB);             // [N+1]
  int* cursor = rowptr + (N + 1);                           // [N]
  int* colsrc = cursor + N;                                 // [E]
  int* gstart = colsrc + E;                                 // [NG+1]

  // stat accumulators must be zero every call
  k_zerof<<<1, 256, 0, stream>>>(sums, 256);

  // CSR build
  k_zeroi<<<(N+255)/256, 256, 0, stream>>>(cursor, N);
  k_hist<<<(E+255)/256, 256, 0, stream>>>(dstI, E, cursor);
  k_scan<<<1, 1024, 0, stream>>>(cursor, rowptr, N);
  k_scatter<<<(E+255)/256, 256, 0, stream>>>(srcI, dstI, E, cursor, colsrc);
  k_gstart<<<(NG+256)/256, 256, 0, stream>>>(batch, N, gstart);

  // weights -> bf16 transposed [n][k]
  const dim3 tb32(32, 8);
  k_castT<<<dim3(H/32, H/32, LNUM), tb32, 0, stream>>>(conv_W1, W1t, H, H);
  k_castT<<<dim3(H/32, H/32, LNUM), tb32, 0, stream>>>(conv_W2, W2t, H, H);
  k_castT<<<dim3(EMB/32, EMB/32, 3), tb32, 0, stream>>>(lW, lWt, EMB, EMB);
  k_castT<<<dim3(EMB/32, EMB/32, 1), tb32, 0, stream>>>(lsW, lsWt, EMB, EMB);

  const float invn = 1.0f / (float)N;
  const dim3 gconv((N + 127)/128, 1);           // N=128 output cols
  const int nbn = ((size_t)N*32 + 255)/256;

  for (int l = 0; l < LNUM; ++l){
    if (l == 0)
      k_agg<false><<<N, 128, 0, stream>>>(x, H, rowptr, colsrc, epsv, hpre);
    else
      k_agg<true><<<N, 128, 0, stream>>>(xall + (size_t)(l-1)*H, EMB, rowptr, colsrc,
                                         epsv + l, hpre);

    k_mm<false,false,false><<<gconv, 256, 0, stream>>>(
        hpre, H, W1t + (size_t)l*H*H, H, conv_b1 + l*H,
        nullptr, 0, tbuf, H, N, H);
    k_stats<<<512, 256, 0, stream>>>(tbuf, N, sums, sumsq);
    k_bnfin<<<1, 128, 0, stream>>>(sums, sumsq, conv_g1 + l*H, conv_be1 + l*H,
                                   bnscale, bnshift, invn);
    k_bnapply<<<nbn, 256, 0, stream>>>(tbuf, bnscale, bnshift, tb16, H, N);

    k_mm<false,false,false><<<gconv, 256, 0, stream>>>(
        tb16, H, W2t + (size_t)l*H*H, H, conv_b2 + l*H,
        nullptr, 0, ubuf, H, N, H);
    k_stats<<<512, 256, 0, stream>>>(ubuf, N, sums, sumsq);
    k_bnfin<<<1, 128, 0, stream>>>(sums, sumsq, bn_g + l*H, bn_b + l*H,
                                   bnscale, bnshift, invn);
    k_bnapply<<<nbn, 256, 0, stream>>>(ubuf, bnscale, bnshift, xall + (size_t)l*H, EMB, N);
  }

  // pooling + per-layer prediction heads -> xcat (third output)
  k_pool<<<NG, EMB, 0, stream>>>(xall, gstart, pooled);
  k_pred<<<dim3(NG, LNUM), 128, 0, stream>>>(pooled, pred_W, pred_b, XC);

  // graph FF (f32, M=512): GE = relu-chain(XC) + XC @ gsW + gsb
  const dim3 gg((NG + 63)/64, EMB/64);
  k_gemm64<false,false><<<gg, 256, 0, stream>>>(XC, EMB, gsW, EMB, gsb,
                                                nullptr, 0, GE, EMB, NG, EMB, EMB);
  k_gemm64<true,false><<<gg, 256, 0, stream>>>(XC, EMB, gW, EMB, gb,
                                               nullptr, 0, gtmp1, EMB, NG, EMB, EMB);
  k_gemm64<true,false><<<gg, 256, 0, stream>>>(gtmp1, EMB, gW + (size_t)EMB*EMB, EMB, gb + EMB,
                                               nullptr, 0, gtmp2, EMB, NG, EMB, EMB);
  k_gemm64<true,true><<<gg, 256, 0, stream>>>(gtmp2, EMB, gW + (size_t)2*EMB*EMB, EMB, gb + 2*EMB,
                                              GE, EMB, GE, EMB, NG, EMB, EMB);

  // node FF (bf16 MFMA): NE = relu-chain(xall) + xall @ lsW + lsb
  const dim3 gn((N + 127)/128, EMB/128);        // (391, 5)
  k_mm<false,false,false><<<gn, 256, 0, stream>>>(
      xall, EMB, lsWt, EMB, lsb, nullptr, 0, NE, EMB, N, EMB);
  k_mm<true,false,true><<<gn, 256, 0, stream>>>(
      xall, EMB, lWt, EMB, lb, nullptr, 0, h1, EMB, N, EMB);
  k_mm<true,false,true><<<gn, 256, 0, stream>>>(
      h1, EMB, lWt + (size_t)EMB*EMB, EMB, lb + EMB, nullptr, 0, h2, EMB, N, EMB);
  k_mm<true,true,false><<<gn, 256, 0, stream>>>(
      h2, EMB, lWt + (size_t)2*EMB*EMB, EMB, lb + 2*EMB, NE, EMB, NE, EMB, N, EMB);
}

// Round 3
// 1684.221 us; speedup vs baseline: 2.0272x; 1.0784x over previous
//
#include <hip/hip_runtime.h>

constexpr int H    = 128;
constexpr int LNUM = 5;
constexpr int NG   = 512;
constexpr int EMB  = 640;   // LNUM * H
constexpr float BN_EPS = 1e-5f;

typedef __attribute__((ext_vector_type(8))) short bf16x8;
typedef __attribute__((ext_vector_type(4))) float f32x4;
typedef unsigned short ushort_t;

__device__ inline unsigned short f2bf(float f){
  unsigned u = __builtin_bit_cast(unsigned, f);
  u += 0x7FFF + ((u >> 16) & 1);
  return (unsigned short)(u >> 16);
}
__device__ inline float bf2f(unsigned short h){
  unsigned u = ((unsigned)h) << 16;
  return __builtin_bit_cast(float, u);
}

// ---------------- utility ----------------
__global__ void k_zerof(float* p, int n){
  int i = blockIdx.x*256 + threadIdx.x;
  if (i < n) p[i] = 0.f;
}
__global__ void k_zeroi(int* p, int n){
  int i = blockIdx.x*256 + threadIdx.x;
  if (i < n) p[i] = 0;
}

// ---------------- CSR build ----------------
__global__ void k_hist(const int* __restrict__ dst, int E, int* deg){
  int e = blockIdx.x*256 + threadIdx.x;
  if (e < E) atomicAdd(&deg[dst[e]], 1);
}

__global__ __launch_bounds__(1024) void k_scan(int* degcur, int* __restrict__ rowptr, int n){
  __shared__ int sh[1024];
  __shared__ int carry;
  int tid = threadIdx.x;
  if (tid == 0){ carry = 0; rowptr[0] = 0; }
  __syncthreads();
  for (int base = 0; base < n; base += 1024){
    int v = (base + tid < n) ? degcur[base + tid] : 0;
    sh[tid] = v;
    __syncthreads();
    for (int off = 1; off < 1024; off <<= 1){
      int t = (tid >= off) ? sh[tid - off] : 0;
      __syncthreads();
      sh[tid] += t;
      __syncthreads();
    }
    int incl = sh[tid] + carry;
    if (base + tid < n){ rowptr[base + tid + 1] = incl; degcur[base + tid] = incl - v; }
    int tot = sh[1023];
    __syncthreads();
    if (tid == 0) carry += tot;
    __syncthreads();
  }
}

__global__ void k_scatter(const int* __restrict__ src, const int* __restrict__ dst,
                          int E, int* cursor, int* __restrict__ colsrc){
  int e = blockIdx.x*256 + threadIdx.x;
  if (e < E){
    int d = dst[e];
    int pos = atomicAdd(&cursor[d], 1);
    colsrc[pos] = src[e];
  }
}

__global__ void k_gstart(const int* __restrict__ batch, int N, int* __restrict__ gstart){
  int g = blockIdx.x*256 + threadIdx.x;
  if (g <= NG){
    int lo = 0, hi = N;
    while (lo < hi){
      int mid = (lo + hi) >> 1;
      if (batch[mid] < g) lo = mid + 1; else hi = mid;
    }
    gstart[g] = lo;
  }
}

// ---- weight cast+transpose: W[k][n] f32 -> Wt[n][ldt] bf16 at column offset koff ----
__global__ void k_castT(const float* __restrict__ W, unsigned short* __restrict__ Wt,
                        int K, int Nn, int ldt, int koff){
  __shared__ float sh[32][33];
  const size_t in_off  = (size_t)blockIdx.z * K * Nn;
  const size_t out_off = (size_t)blockIdx.z * Nn * ldt;
  int n0 = blockIdx.x*32, k0 = blockIdx.y*32;
  int tx = threadIdx.x, ty = threadIdx.y;   // 32 x 8
  for (int r = ty; r < 32; r += 8)
    sh[r][tx] = W[in_off + (size_t)(k0 + r)*Nn + n0 + tx];
  __syncthreads();
  for (int r = ty; r < 32; r += 8)
    Wt[out_off + (size_t)(n0 + r)*ldt + koff + k0 + tx] = f2bf(sh[tx][r]);
}

__global__ void k_bias2(const float* __restrict__ a, const float* __restrict__ b,
                        float* __restrict__ o){
  int i = threadIdx.x;
  o[i] = a[i] + b[i];
}

// ------- GIN aggregation: wave per node, lane handles 2 feats via u32 -------
template<bool IN_BF16>
__global__ __launch_bounds__(256) void k_agg(const void* __restrict__ hin_, int ldh,
                                             const int* __restrict__ rowptr,
                                             const int* __restrict__ colsrc,
                                             const float* __restrict__ epsp,
                                             unsigned short* __restrict__ outp, int nN){
  int node = blockIdx.x*4 + (threadIdx.x >> 6);
  if (node >= nN) return;
  int lane = threadIdx.x & 63;
  float a0, a1;
  if (IN_BF16){
    unsigned u = ((const unsigned*)hin_)[((size_t)node*ldh >> 1) + lane];
    a0 = bf2f((unsigned short)u); a1 = bf2f((unsigned short)(u >> 16));
  } else {
    float2 f = ((const float2*)hin_)[((size_t)node*ldh >> 1) + lane];
    a0 = f.x; a1 = f.y;
  }
  float ep = 1.0f + *epsp;
  a0 *= ep; a1 *= ep;
  int e1 = rowptr[node+1];
  for (int e = rowptr[node]; e < e1; ++e){
    int s = colsrc[e];
    if (IN_BF16){
      unsigned u = ((const unsigned*)hin_)[((size_t)s*ldh >> 1) + lane];
      a0 += bf2f((unsigned short)u); a1 += bf2f((unsigned short)(u >> 16));
    } else {
      float2 f = ((const float2*)hin_)[((size_t)s*ldh >> 1) + lane];
      a0 += f.x; a1 += f.y;
    }
  }
  ((unsigned*)outp)[((size_t)node*H >> 1) + lane] =
      (unsigned)f2bf(a0) | ((unsigned)f2bf(a1) << 16);
}

// ---------------- BN finalize ----------------
__global__ void k_bnfin(float* sums, float* sumsq,
                        const float* __restrict__ g, const float* __restrict__ b,
                        float* __restrict__ scale, float* __restrict__ shift, float invn){
  int c = threadIdx.x;
  float m = sums[c]*invn;
  float v = sumsq[c]*invn - m*m;
  float inv = rsqrtf(v + BN_EPS);
  float sc = g[c]*inv;
  scale[c] = sc;
  shift[c] = b[c] - m*sc;
  sums[c] = 0.f; sumsq[c] = 0.f;
}

// out[r][c] = bf16(relu(scale[c]*bf2f(U[r][c]) + shift[c])), out leading-dim ldo
__global__ __launch_bounds__(256) void k_bnapply(const unsigned short* __restrict__ U,
                                                 const float* __restrict__ scale,
                                                 const float* __restrict__ shift,
                                                 unsigned short* __restrict__ out,
                                                 int ldo, int n){
  int i = blockIdx.x*256 + threadIdx.x;
  int total = n * (H/4);
  if (i < total){
    int r = i >> 5;
    int c4 = (i & 31) << 2;
    uint2 up = *(const uint2*)(U + (size_t)r*H + c4);
    float4 sc = *(const float4*)(scale + c4);
    float4 sf = *(const float4*)(shift + c4);
    float a = fmaxf(fmaf(sc.x, bf2f((unsigned short)up.x),        sf.x), 0.f);
    float b = fmaxf(fmaf(sc.y, bf2f((unsigned short)(up.x>>16)),  sf.y), 0.f);
    float c = fmaxf(fmaf(sc.z, bf2f((unsigned short)up.y),        sf.z), 0.f);
    float d = fmaxf(fmaf(sc.w, bf2f((unsigned short)(up.y>>16)),  sf.w), 0.f);
    uint2 o;
    o.x = (unsigned)f2bf(a) | ((unsigned)f2bf(b) << 16);
    o.y = (unsigned)f2bf(c) | ((unsigned)f2bf(d) << 16);
    *(uint2*)(out + (size_t)r*ldo + c4) = o;
  }
}

// ---------------- pooling + prediction heads ----------------
__global__ __launch_bounds__(320) void k_pool(const unsigned short* __restrict__ xall,
                                              const int* __restrict__ gstart,
                                              float* __restrict__ pooled){
  int g = blockIdx.x;
  int t = threadIdx.x;              // 320 threads, 2 feats each
  int n0 = gstart[g], n1 = gstart[g+1];
  float a0 = 0.f, a1 = 0.f;
  for (int n = n0; n < n1; ++n){
    unsigned u = ((const unsigned*)xall)[(size_t)n*(EMB/2) + t];
    a0 += bf2f((unsigned short)u); a1 += bf2f((unsigned short)(u >> 16));
  }
  *(float2*)(pooled + (size_t)g*EMB + 2*t) = make_float2(a0, a1);
}

__global__ __launch_bounds__(128) void k_pred(const float* __restrict__ pooled,
                                              const float* __restrict__ W,
                                              const float* __restrict__ b,
                                              float* __restrict__ xcat){
  int g = blockIdx.x, l = blockIdx.y, o = threadIdx.x;
  __shared__ float sh[128];
  sh[o] = pooled[(size_t)g*EMB + l*H + o];
  __syncthreads();
  const float* Wl = W + (size_t)l*H*H;
  float acc = b[l*H + o];
  for (int k = 0; k < H; ++k) acc = fmaf(sh[k], Wl[k*H + o], acc);
  xcat[(size_t)g*EMB + l*H + o] = acc;
}

// ---------------- bf16 MFMA GEMM, 128x128 tile, BK=64, double-buffered ----------------
// blockIdx.x = COLUMN block (fast -> A-tile reuse in L2/L3), blockIdx.y = row block.
// DUAL: A rows are [A | A2] concatenated along K (each KA=K/2 wide); B is [N][K].
template<bool RELU, bool STATS, bool OUT_BF16, bool DUAL>
__global__ __launch_bounds__(256) void k_mm(
    const unsigned short* __restrict__ A, int lda,
    const unsigned short* __restrict__ A2,
    const unsigned short* __restrict__ Bt, int ldb,
    const float* __restrict__ bias,
    void* __restrict__ Cv, int ldc,
    float* sums, float* sumsq,
    int M, int K)
{
  __shared__ unsigned short As[2][128*64];   // 2 x 16 KB
  __shared__ unsigned short Bs[2][128*64];
  const int tid  = threadIdx.x;
  const int lane = tid & 63;
  const int w    = tid >> 6;
  const int wr   = w >> 1, wc = w & 1;
  const int col0 = blockIdx.x * 128;
  const int row0 = blockIdx.y * 128;
  const int KA   = DUAL ? (K >> 1) : K;

  // staging sources: wave w owns LDS bytes [w*4K, w*4K+4K) per tile, 4 chunks of 1KB
  const unsigned short *sA[4], *sA2[4], *sB[4];
  int dOff[4];
#pragma unroll
  for (int j = 0; j < 4; ++j){
    int d = w*4096 + j*1024 + lane*16;        // linear LDS byte dest
    int m = d >> 7;                           // tile row of this dest
    int inner = (d & 127) ^ ((m & 7) << 4);   // inverse-swizzled byte-in-row
    int gm = row0 + m; if (gm > M-1) gm = M-1;
    sA[j]  = A  + (size_t)gm*lda + (inner >> 1);
    if (DUAL) sA2[j] = A2 + (size_t)gm*lda + (inner >> 1);
    sB[j]  = Bt + (size_t)(col0 + m)*ldb + (inner >> 1);
    dOff[j] = w*4096 + j*1024;
  }

  f32x4 acc[4][4];
#pragma unroll
  for (int i = 0; i < 4; ++i)
#pragma unroll
    for (int j = 0; j < 4; ++j)
      acc[i][j] = (f32x4){0.f, 0.f, 0.f, 0.f};

  auto STAGE = [&](int buf, int kt){
    int k0 = kt*64;
    int ka = k0;
    bool second = DUAL && (k0 >= KA);
    if (second) ka = k0 - KA;
#pragma unroll
    for (int j = 0; j < 4; ++j){
      const unsigned short* srcA = second ? (sA2[j] + ka) : (sA[j] + ka);
      __builtin_amdgcn_global_load_lds(
          (const __attribute__((address_space(1))) void*)srcA,
          (__attribute__((address_space(3))) void*)((char*)&As[buf][0] + dOff[j]),
          16, 0, 0);
    }
#pragma unroll
    for (int j = 0; j < 4; ++j)
      __builtin_amdgcn_global_load_lds(
          (const __attribute__((address_space(1))) void*)(sB[j] + k0),
          (__attribute__((address_space(3))) void*)((char*)&Bs[buf][0] + dOff[j]),
          16, 0, 0);
  };

  auto COMPUTE = [&](int buf){
    const char* Ab = (const char*)&As[buf][0];
    const char* Bb = (const char*)&Bs[buf][0];
#pragma unroll
    for (int kk = 0; kk < 2; ++kk){
      const int kb = kk*64 + ((lane >> 4) << 4);
      bf16x8 af[4], bfr[4];
#pragma unroll
      for (int i = 0; i < 4; ++i){
        int row = wr*64 + i*16 + (lane & 15);
        int ab  = (row*128 + kb) ^ ((row & 7) << 4);
        af[i] = *(const bf16x8*)(Ab + ab);
        int col = wc*64 + i*16 + (lane & 15);
        int bb  = (col*128 + kb) ^ ((col & 7) << 4);
        bfr[i] = *(const bf16x8*)(Bb + bb);
      }
#pragma unroll
      for (int i = 0; i < 4; ++i)
#pragma unroll
        for (int j = 0; j < 4; ++j)
          acc[i][j] = __builtin_amdgcn_mfma_f32_16x16x32_bf16(af[i], bfr[j], acc[i][j], 0, 0, 0);
    }
  };

  const int NT = K / 64;
  STAGE(0, 0);
  asm volatile("s_waitcnt vmcnt(0)" ::: "memory");
  __syncthreads();
  int cur = 0;
  for (int t = 0; t < NT-1; ++t){
    STAGE(cur ^ 1, t + 1);
    COMPUTE(cur);
    asm volatile("s_waitcnt vmcnt(0)" ::: "memory");
    __syncthreads();
    cur ^= 1;
  }
  COMPUTE(cur);

  // ---- fused BN stats: per-column sum / sumsq over valid rows ----
  if (STATS){
#pragma unroll
    for (int j = 0; j < 4; ++j){
      int col = col0 + wc*64 + j*16 + (lane & 15);
      float bs = bias[col];
      float s = 0.f, q = 0.f;
#pragma unroll
      for (int i = 0; i < 4; ++i){
        int rb = row0 + wr*64 + i*16 + ((lane >> 4) << 2);
#pragma unroll
        for (int r = 0; r < 4; ++r){
          if (rb + r < M){
            float v = acc[i][j][r] + bs;
            s += v; q += v*v;
          }
        }
      }
      s += __shfl_xor(s, 16); q += __shfl_xor(q, 16);
      s += __shfl_xor(s, 32); q += __shfl_xor(q, 32);
      if (lane < 16){
        atomicAdd(&sums[col], s);
        atomicAdd(&sumsq[col], q);
      }
    }
  }

  // ---- epilogue ----
  float* Cf = (float*)Cv;
  unsigned short* Cb = (unsigned short*)Cv;
#pragma unroll
  for (int j = 0; j < 4; ++j){
    int col = col0 + wc*64 + j*16 + (lane & 15);
    float bs = bias[col];
#pragma unroll
    for (int i = 0; i < 4; ++i){
      int rb = row0 + wr*64 + i*16 + ((lane >> 4) << 2);
#pragma unroll
      for (int r = 0; r < 4; ++r){
        int row = rb + r;
        if (row < M){
          float v = acc[i][j][r] + bs;
          if (RELU) v = fmaxf(v, 0.f);
          if (OUT_BF16) Cb[(size_t)row*ldc + col] = f2bf(v);
          else          Cf[(size_t)row*ldc + col] = v;
        }
      }
    }
  }
}

// ---------------- f32 GEMM 64x64 (graph FF, M=512) ----------------
template<bool RELU, bool ADD_D>
__global__ __launch_bounds__(256) void k_gemm64(
    const float* __restrict__ A, int lda,
    const float* __restrict__ B, int ldb,
    const float* __restrict__ bias,
    const float* D, int ldd,
    float* C, int ldc,
    int M, int N, int K)
{
  __shared__ float As[32][68];
  __shared__ float Bs[32][64];
  const int tid  = threadIdx.x;
  const int tx   = tid & 15;
  const int ty   = tid >> 4;
  const int row0 = blockIdx.x * 64;
  const int col0 = blockIdx.y * 64;
  const int am = tid >> 3;
  const int ak = (tid & 7) << 2;
  const int bk = tid >> 4;
  const int bn = (tid & 15) << 2;
  float acc[4][4] = {};

  for (int k0 = 0; k0 < K; k0 += 32){
#pragma unroll
    for (int h = 0; h < 2; ++h){
      int m  = am + h*32;
      int gr = row0 + m;
      float4 v = make_float4(0.f, 0.f, 0.f, 0.f);
      if (gr < M) v = *(const float4*)(A + (size_t)gr*lda + k0 + ak);
      As[ak+0][m]=v.x; As[ak+1][m]=v.y; As[ak+2][m]=v.z; As[ak+3][m]=v.w;
    }
#pragma unroll
    for (int h = 0; h < 2; ++h){
      int kk = bk + h*16;
      *(float4*)(&Bs[kk][bn]) = *(const float4*)(B + (size_t)(k0+kk)*ldb + col0 + bn);
    }
    __syncthreads();
#pragma unroll 8
    for (int k = 0; k < 32; ++k){
      float4 a = *(const float4*)(&As[k][ty<<2]);
      float4 b = *(const float4*)(&Bs[k][tx<<2]);
      float av[4] = {a.x,a.y,a.z,a.w};
      float bv[4] = {b.x,b.y,b.z,b.w};
#pragma unroll
      for (int i = 0; i < 4; ++i)
#pragma unroll
        for (int j = 0; j < 4; ++j)
          acc[i][j] = fmaf(av[i], bv[j], acc[i][j]);
    }
    __syncthreads();
  }

  const int col = col0 + (tx<<2);
  float4 bv = *(const float4*)(bias + col);
#pragma unroll
  for (int i = 0; i < 4; ++i){
    int row = row0 + (ty<<2) + i;
    if (row < M){
      float r[4] = {acc[i][0]+bv.x, acc[i][1]+bv.y, acc[i][2]+bv.z, acc[i][3]+bv.w};
      if (RELU){
#pragma unroll
        for (int j = 0; j < 4; ++j) r[j] = fmaxf(r[j], 0.f);
      }
      if (ADD_D){
        float4 d = *(const float4*)(D + (size_t)row*ldd + col);
        r[0]+=d.x; r[1]+=d.y; r[2]+=d.z; r[3]+=d.w;
      }
      *(float4*)(C + (size_t)row*ldc + col) = make_float4(r[0],r[1],r[2],r[3]);
    }
  }
}

// ---------------- host ----------------
extern "C" void kernel_launch(void* const* d_in, const int* in_sizes, int n_in,
                              void* d_out, int out_size, void* d_ws, size_t ws_size,
                              hipStream_t stream) {
  const float* x        = (const float*)d_in[0];
  const int*   ei       = (const int*)d_in[1];
  const int*   batch    = (const int*)d_in[2];
  const float* conv_W1  = (const float*)d_in[3];
  const float* conv_b1  = (const float*)d_in[4];
  const float* conv_g1  = (const float*)d_in[5];
  const float* conv_be1 = (const float*)d_in[6];
  const float* conv_W2  = (const float*)d_in[7];
  const float* conv_b2  = (const float*)d_in[8];
  const float* epsv     = (const float*)d_in[9];
  const float* bn_g     = (const float*)d_in[10];
  const float* bn_b     = (const float*)d_in[11];
  const float* pred_W   = (const float*)d_in[12];
  const float* pred_b   = (const float*)d_in[13];
  const float* gW       = (const float*)d_in[14];
  const float* gb       = (const float*)d_in[15];
  const float* gsW      = (const float*)d_in[16];
  const float* gsb      = (const float*)d_in[17];
  const float* lW       = (const float*)d_in[18];
  const float* lb       = (const float*)d_in[19];
  const float* lsW      = (const float*)d_in[20];
  const float* lsb      = (const float*)d_in[21];

  const int N = in_sizes[0] / H;
  const int E = in_sizes[1] / 2;
  const int* srcI = ei;
  const int* dstI = ei + E;

  float* out = (float*)d_out;
  float* GE = out;                              // [NG][EMB]
  float* NE = out + (size_t)NG*EMB;             // [N][EMB] f32
  float* XC = NE + (size_t)N*EMB;               // [NG][EMB]

  // ---- workspace layout ----
  unsigned short* xall = (unsigned short*)d_ws;             // [N][EMB] bf16
  unsigned short* h1   = xall + (size_t)N*EMB;              // [N][EMB] bf16
  unsigned short* h2   = h1 + (size_t)N*EMB;                // [N][EMB] bf16
  // conv-loop aliases inside h1 region (3*N*H < N*EMB)
  unsigned short* hpre = h1;                                // [N][H]
  unsigned short* ub   = h1 + (size_t)N*H;                  // [N][H]
  unsigned short* tb   = h1 + (size_t)2*N*H;                // [N][H]

  float* pooled  = (float*)(h2 + (size_t)N*EMB);            // [NG][EMB]
  float* gtmp1   = pooled + (size_t)NG*EMB;
  float* gtmp2   = gtmp1 + (size_t)NG*EMB;
  float* sums    = gtmp2 + (size_t)NG*EMB;                  // [128]
  float* sumsq   = sums + 128;
  float* bnscale = sumsq + 128;
  float* bnshift = bnscale + 128;
  float* biasNE  = bnshift + 128;                           // [640]
  unsigned short* W1t   = (unsigned short*)(biasNE + EMB);  // [L][H][H]
  unsigned short* W2t   = W1t + (size_t)LNUM*H*H;
  unsigned short* lWt01 = W2t + (size_t)LNUM*H*H;           // [2][EMB][EMB]
  unsigned short* Wcat  = lWt01 + (size_t)2*EMB*EMB;        // [EMB][2*EMB]
  int* rowptr = (int*)(Wcat + (size_t)2*EMB*EMB);           // [N+1]
  int* cursor = rowptr + (N + 1);                           // [N]
  int* colsrc = cursor + N;                                 // [E]
  int* gstart = colsrc + E;                                 // [NG+1]

  // stat accumulators must be zero every call
  k_zerof<<<1, 256, 0, stream>>>(sums, 256);

  // CSR build
  k_zeroi<<<(N+255)/256, 256, 0, stream>>>(cursor, N);
  k_hist<<<(E+255)/256, 256, 0, stream>>>(dstI, E, cursor);
  k_scan<<<1, 1024, 0, stream>>>(cursor, rowptr, N);
  k_scatter<<<(E+255)/256, 256, 0, stream>>>(srcI, dstI, E, cursor, colsrc);
  k_gstart<<<(NG+256)/256, 256, 0, stream>>>(batch, N, gstart);

  // weights -> bf16 transposed [n][k]
  const dim3 tb32(32, 8);
  k_castT<<<dim3(H/32, H/32, LNUM), tb32, 0, stream>>>(conv_W1, W1t, H, H, H, 0);
  k_castT<<<dim3(H/32, H/32, LNUM), tb32, 0, stream>>>(conv_W2, W2t, H, H, H, 0);
  k_castT<<<dim3(EMB/32, EMB/32, 2), tb32, 0, stream>>>(lW, lWt01, EMB, EMB, EMB, 0);
  k_castT<<<dim3(EMB/32, EMB/32, 1), tb32, 0, stream>>>(lW + (size_t)2*EMB*EMB, Wcat,
                                                        EMB, EMB, 2*EMB, 0);
  k_castT<<<dim3(EMB/32, EMB/32, 1), tb32, 0, stream>>>(lsW, Wcat, EMB, EMB, 2*EMB, EMB);
  k_bias2<<<1, EMB, 0, stream>>>(lb + (size_t)2*EMB, lsb, biasNE);

  const float invn = 1.0f / (float)N;
  const dim3 gconv(1, (N + 127)/128);           // col-fast layout: x=1 col block
  const int nbn = (N*32 + 255)/256;

  for (int l = 0; l < LNUM; ++l){
    if (l == 0)
      k_agg<false><<<(N+3)/4, 256, 0, stream>>>(x, H, rowptr, colsrc, epsv, hpre, N);
    else
      k_agg<true><<<(N+3)/4, 256, 0, stream>>>(xall + (size_t)(l-1)*H, EMB, rowptr, colsrc,
                                               epsv + l, hpre, N);

    // u = hpre @ W1 + b1  (bf16 out, fused column stats)
    k_mm<false,true,true,false><<<gconv, 256, 0, stream>>>(
        hpre, H, nullptr, W1t + (size_t)l*H*H, H, conv_b1 + l*H,
        ub, H, sums, sumsq, N, H);
    k_bnfin<<<1, 128, 0, stream>>>(sums, sumsq, conv_g1 + l*H, conv_be1 + l*H,
                                   bnscale, bnshift, invn);
    k_bnapply<<<nbn, 256, 0, stream>>>(ub, bnscale, bnshift, tb, H, N);

    // u2 = t @ W2 + b2  (bf16 out, fused column stats)
    k_mm<false,true,true,false><<<gconv, 256, 0, stream>>>(
        tb, H, nullptr, W2t + (size_t)l*H*H, H, conv_b2 + l*H,
        ub, H, sums, sumsq, N, H);
    k_bnfin<<<1, 128, 0, stream>>>(sums, sumsq, bn_g + l*H, bn_b + l*H,
                                   bnscale, bnshift, invn);
    k_bnapply<<<nbn, 256, 0, stream>>>(ub, bnscale, bnshift, xall + (size_t)l*H, EMB, N);
  }

  // pooling + per-layer prediction heads -> xcat
  k_pool<<<NG, 320, 0, stream>>>(xall, gstart, pooled);
  k_pred<<<dim3(NG, LNUM), 128, 0, stream>>>(pooled, pred_W, pred_b, XC);

  // graph FF (f32, M=512): GE = relu-chain(XC) + XC @ gsW + gsb
  const dim3 gg((NG + 63)/64, EMB/64);
  k_gemm64<false,false><<<gg, 256, 0, stream>>>(XC, EMB, gsW, EMB, gsb,
                                                nullptr, 0, GE, EMB, NG, EMB, EMB);
  k_gemm64<true,false><<<gg, 256, 0, stream>>>(XC, EMB, gW, EMB, gb,
                                               nullptr, 0, gtmp1, EMB, NG, EMB, EMB);
  k_gemm64<true,false><<<gg, 256, 0, stream>>>(gtmp1, EMB, gW + (size_t)EMB*EMB, EMB, gb + EMB,
                                               nullptr, 0, gtmp2, EMB, NG, EMB, EMB);
  k_gemm64<true,true><<<gg, 256, 0, stream>>>(gtmp2, EMB, gW + (size_t)2*EMB*EMB, EMB, gb + 2*EMB,
                                              GE, EMB, GE, EMB, NG, EMB, EMB);

  // node FF (bf16 MFMA, col-fast grid):
  const dim3 gn(EMB/128, (N + 127)/128);        // (5, 391)
  // h1 = relu(xall @ lW0 + lb0)
  k_mm<true,false,true,false><<<gn, 256, 0, stream>>>(
      xall, EMB, nullptr, lWt01, EMB, lb, h1, EMB, nullptr, nullptr, N, EMB);
  // h2 = relu(h1 @ lW1 + lb1)
  k_mm<true,false,true,false><<<gn, 256, 0, stream>>>(
      h1, EMB, nullptr, lWt01 + (size_t)EMB*EMB, EMB, lb + EMB,
      h2, EMB, nullptr, nullptr, N, EMB);
  // NE = [h2 | xall] @ [lW2 ; lsW] + (lb2 + lsb)   (dual-A, K=1280, f32 out)
  k_mm<false,false,false,true><<<gn, 256, 0, stream>>>(
      h2, EMB, xall, Wcat, 2*EMB, biasNE, NE, EMB, nullptr, nullptr, N, 2*EMB);
}

// Round 4
// 1560.556 us; speedup vs baseline: 2.1878x; 1.0792x over previous
//
#include <hip/hip_runtime.h>

constexpr int H    = 128;
constexpr int LNUM = 5;
constexpr int NG   = 512;
constexpr int EMB  = 640;   // LNUM * H
constexpr float BN_EPS = 1e-5f;

typedef __attribute__((ext_vector_type(8))) short bf16x8;
typedef __attribute__((ext_vector_type(4))) float f32x4;

__device__ inline unsigned short f2bf(float f){
  unsigned u = __builtin_bit_cast(unsigned, f);
  u += 0x7FFF + ((u >> 16) & 1);
  return (unsigned short)(u >> 16);
}
__device__ inline float bf2f(unsigned short h){
  unsigned u = ((unsigned)h) << 16;
  return __builtin_bit_cast(float, u);
}

// bijective XCD chunk swizzle (m204): consecutive wg ids land on one XCD
__device__ inline int xcd_swz(int bid, int nwg){
  int q = nwg >> 3, r = nwg & 7;
  int xcd = bid & 7, idx = bid >> 3;
  return (xcd < r ? xcd*(q+1) : r*(q+1) + (xcd-r)*q) + idx;
}

// ---------------- utility ----------------
__global__ void k_zerof(float* p, int n){
  int i = blockIdx.x*256 + threadIdx.x;
  if (i < n) p[i] = 0.f;
}
__global__ void k_zeroi(int* p, int n){
  int i = blockIdx.x*256 + threadIdx.x;
  if (i < n) p[i] = 0;
}

// ---------------- CSR build ----------------
__global__ void k_hist(const int* __restrict__ dst, int E, int* deg){
  int e = blockIdx.x*256 + threadIdx.x;
  if (e < E) atomicAdd(&deg[dst[e]], 1);
}

__global__ __launch_bounds__(1024) void k_scan(int* degcur, int* __restrict__ rowptr, int n){
  __shared__ int sh[1024];
  __shared__ int carry;
  int tid = threadIdx.x;
  if (tid == 0){ carry = 0; rowptr[0] = 0; }
  __syncthreads();
  for (int base = 0; base < n; base += 1024){
    int v = (base + tid < n) ? degcur[base + tid] : 0;
    sh[tid] = v;
    __syncthreads();
    for (int off = 1; off < 1024; off <<= 1){
      int t = (tid >= off) ? sh[tid - off] : 0;
      __syncthreads();
      sh[tid] += t;
      __syncthreads();
    }
    int incl = sh[tid] + carry;
    if (base + tid < n){ rowptr[base + tid + 1] = incl; degcur[base + tid] = incl - v; }
    int tot = sh[1023];
    __syncthreads();
    if (tid == 0) carry += tot;
    __syncthreads();
  }
}

__global__ void k_scatter(const int* __restrict__ src, const int* __restrict__ dst,
                          int E, int* cursor, int* __restrict__ colsrc){
  int e = blockIdx.x*256 + threadIdx.x;
  if (e < E){
    int d = dst[e];
    int pos = atomicAdd(&cursor[d], 1);
    colsrc[pos] = src[e];
  }
}

__global__ void k_gstart(const int* __restrict__ batch, int N, int* __restrict__ gstart){
  int g = blockIdx.x*256 + threadIdx.x;
  if (g <= NG){
    int lo = 0, hi = N;
    while (lo < hi){
      int mid = (lo + hi) >> 1;
      if (batch[mid] < g) lo = mid + 1; else hi = mid;
    }
    gstart[g] = lo;
  }
}

// ---- weight cast+transpose: W[k][n] f32 -> Wt[n][ldt] bf16 at column offset koff ----
__global__ void k_castT(const float* __restrict__ W, unsigned short* __restrict__ Wt,
                        int K, int Nn, int ldt, int koff){
  __shared__ float sh[32][33];
  const size_t in_off  = (size_t)blockIdx.z * K * Nn;
  const size_t out_off = (size_t)blockIdx.z * Nn * ldt;
  int n0 = blockIdx.x*32, k0 = blockIdx.y*32;
  int tx = threadIdx.x, ty = threadIdx.y;   // 32 x 8
  for (int r = ty; r < 32; r += 8)
    sh[r][tx] = W[in_off + (size_t)(k0 + r)*Nn + n0 + tx];
  __syncthreads();
  for (int r = ty; r < 32; r += 8)
    Wt[out_off + (size_t)(n0 + r)*ldt + koff + k0 + tx] = f2bf(sh[tx][r]);
}

__global__ void k_bias2(const float* __restrict__ a, const float* __restrict__ b,
                        float* __restrict__ o){
  int i = threadIdx.x;
  o[i] = a[i] + b[i];
}

// ------- GIN aggregation: wave per node, lane handles 2 feats via u32 -------
template<bool IN_BF16>
__global__ __launch_bounds__(256) void k_agg(const void* __restrict__ hin_, int ldh,
                                             const int* __restrict__ rowptr,
                                             const int* __restrict__ colsrc,
                                             const float* __restrict__ epsp,
                                             unsigned short* __restrict__ outp, int nN){
  int node = blockIdx.x*4 + (threadIdx.x >> 6);
  if (node >= nN) return;
  int lane = threadIdx.x & 63;
  float a0, a1;
  if (IN_BF16){
    unsigned u = ((const unsigned*)hin_)[((size_t)node*ldh >> 1) + lane];
    a0 = bf2f((unsigned short)u); a1 = bf2f((unsigned short)(u >> 16));
  } else {
    float2 f = ((const float2*)hin_)[((size_t)node*ldh >> 1) + lane];
    a0 = f.x; a1 = f.y;
  }
  float ep = 1.0f + *epsp;
  a0 *= ep; a1 *= ep;
  int e1 = rowptr[node+1];
  for (int e = rowptr[node]; e < e1; ++e){
    int s = colsrc[e];
    if (IN_BF16){
      unsigned u = ((const unsigned*)hin_)[((size_t)s*ldh >> 1) + lane];
      a0 += bf2f((unsigned short)u); a1 += bf2f((unsigned short)(u >> 16));
    } else {
      float2 f = ((const float2*)hin_)[((size_t)s*ldh >> 1) + lane];
      a0 += f.x; a1 += f.y;
    }
  }
  ((unsigned*)outp)[((size_t)node*H >> 1) + lane] =
      (unsigned)f2bf(a0) | ((unsigned)f2bf(a1) << 16);
}

// ---------------- BN finalize ----------------
__global__ void k_bnfin(float* sums, float* sumsq,
                        const float* __restrict__ g, const float* __restrict__ b,
                        float* __restrict__ scale, float* __restrict__ shift, float invn){
  int c = threadIdx.x;
  float m = sums[c]*invn;
  float v = sumsq[c]*invn - m*m;
  float inv = rsqrtf(v + BN_EPS);
  float sc = g[c]*inv;
  scale[c] = sc;
  shift[c] = b[c] - m*sc;
  sums[c] = 0.f; sumsq[c] = 0.f;
}

// out[r][c] = bf16(relu(scale[c]*bf2f(U[r][c]) + shift[c])), out leading-dim ldo
__global__ __launch_bounds__(256) void k_bnapply(const unsigned short* __restrict__ U,
                                                 const float* __restrict__ scale,
                                                 const float* __restrict__ shift,
                                                 unsigned short* __restrict__ out,
                                                 int ldo, int n){
  int i = blockIdx.x*256 + threadIdx.x;
  int total = n * (H/4);
  if (i < total){
    int r = i >> 5;
    int c4 = (i & 31) << 2;
    uint2 up = *(const uint2*)(U + (size_t)r*H + c4);
    float4 sc = *(const float4*)(scale + c4);
    float4 sf = *(const float4*)(shift + c4);
    float a = fmaxf(fmaf(sc.x, bf2f((unsigned short)up.x),        sf.x), 0.f);
    float b = fmaxf(fmaf(sc.y, bf2f((unsigned short)(up.x>>16)),  sf.y), 0.f);
    float c = fmaxf(fmaf(sc.z, bf2f((unsigned short)up.y),        sf.z), 0.f);
    float d = fmaxf(fmaf(sc.w, bf2f((unsigned short)(up.y>>16)),  sf.w), 0.f);
    uint2 o;
    o.x = (unsigned)f2bf(a) | ((unsigned)f2bf(b) << 16);
    o.y = (unsigned)f2bf(c) | ((unsigned)f2bf(d) << 16);
    *(uint2*)(out + (size_t)r*ldo + c4) = o;
  }
}

// ---------------- pooling + prediction heads ----------------
__global__ __launch_bounds__(320) void k_pool(const unsigned short* __restrict__ xall,
                                              const int* __restrict__ gstart,
                                              float* __restrict__ pooled){
  int g = blockIdx.x;
  int t = threadIdx.x;              // 320 threads, 2 feats each
  int n0 = gstart[g], n1 = gstart[g+1];
  float a0 = 0.f, a1 = 0.f;
  for (int n = n0; n < n1; ++n){
    unsigned u = ((const unsigned*)xall)[(size_t)n*(EMB/2) + t];
    a0 += bf2f((unsigned short)u); a1 += bf2f((unsigned short)(u >> 16));
  }
  *(float2*)(pooled + (size_t)g*EMB + 2*t) = make_float2(a0, a1);
}

__global__ __launch_bounds__(128) void k_pred(const float* __restrict__ pooled,
                                              const float* __restrict__ W,
                                              const float* __restrict__ b,
                                              float* __restrict__ xcat){
  int g = blockIdx.x, l = blockIdx.y, o = threadIdx.x;
  __shared__ float sh[128];
  sh[o] = pooled[(size_t)g*EMB + l*H + o];
  __syncthreads();
  const float* Wl = W + (size_t)l*H*H;
  float acc = b[l*H + o];
  for (int k = 0; k < H; ++k) acc = fmaf(sh[k], Wl[k*H + o], acc);
  xcat[(size_t)g*EMB + l*H + o] = acc;
}

// ---------------- bf16 MFMA GEMM, 128x128 tile, BK=64, single-buffer (m97) ----------------
// blockIdx.x = column block (col-fast); XCD chunk swizzle -> A row-tile reuse in L2.
// DUAL: A rows are [A | A2] concatenated along K (each K/2 wide).
template<bool RELU, bool OUT_BF16, bool DUAL>
__global__ __launch_bounds__(256) void k_mm(
    const unsigned short* __restrict__ A, int lda,
    const unsigned short* __restrict__ A2,
    const unsigned short* __restrict__ Bt, int ldb,
    const float* __restrict__ bias,
    void* __restrict__ Cv, int ldc,
    int M, int K)
{
  __shared__ unsigned short As[128*64];   // 16 KB
  __shared__ unsigned short Bs[128*64];   // 16 KB
  const int tid  = threadIdx.x;
  const int lane = tid & 63;
  const int w    = tid >> 6;
  const int wr   = w >> 1, wc = w & 1;

  const int nwg = gridDim.x * gridDim.y;
  const int bid = blockIdx.y * gridDim.x + blockIdx.x;
  const int wg  = xcd_swz(bid, nwg);
  const int col0 = (wg % gridDim.x) * 128;
  const int row0 = (wg / gridDim.x) * 128;
  const int KA   = DUAL ? (K >> 1) : K;

  // staging: wave w owns LDS bytes [w*4K, w*4K+4K) per tile, 4 chunks of 1KB
  const unsigned short *sA[4], *sA2[4], *sB[4];
  int dOff[4];
#pragma unroll
  for (int j = 0; j < 4; ++j){
    int d = w*4096 + j*1024 + lane*16;        // linear LDS byte dest
    int m = d >> 7;                           // tile row of this dest
    int inner = (d & 127) ^ ((m & 7) << 4);   // inverse-swizzled byte-in-row
    int gm = row0 + m; if (gm > M-1) gm = M-1;
    sA[j]  = A  + (size_t)gm*lda + (inner >> 1);
    if (DUAL) sA2[j] = A2 + (size_t)gm*lda + (inner >> 1);
    sB[j]  = Bt + (size_t)(col0 + m)*ldb + (inner >> 1);
    dOff[j] = w*4096 + j*1024;
  }

  f32x4 acc[4][4];
#pragma unroll
  for (int i = 0; i < 4; ++i)
#pragma unroll
    for (int j = 0; j < 4; ++j)
      acc[i][j] = (f32x4){0.f, 0.f, 0.f, 0.f};

  const int NT = K / 64;
  for (int t = 0; t < NT; ++t){
    int k0 = t*64;
    int ka = k0;
    bool second = DUAL && (k0 >= KA);
    if (second) ka = k0 - KA;
#pragma unroll
    for (int j = 0; j < 4; ++j){
      const unsigned short* srcA = second ? (sA2[j] + ka) : (sA[j] + ka);
      __builtin_amdgcn_global_load_lds(
          (const __attribute__((address_space(1))) void*)srcA,
          (__attribute__((address_space(3))) void*)((char*)As + dOff[j]),
          16, 0, 0);
    }
#pragma unroll
    for (int j = 0; j < 4; ++j)
      __builtin_amdgcn_global_load_lds(
          (const __attribute__((address_space(1))) void*)(sB[j] + k0),
          (__attribute__((address_space(3))) void*)((char*)Bs + dOff[j]),
          16, 0, 0);
    asm volatile("s_waitcnt vmcnt(0)" ::: "memory");
    __syncthreads();

#pragma unroll
    for (int kk = 0; kk < 2; ++kk){
      const int kb = kk*64 + ((lane >> 4) << 4);
      bf16x8 af[4], bfr[4];
#pragma unroll
      for (int i = 0; i < 4; ++i){
        int row = wr*64 + i*16 + (lane & 15);
        int ab  = (row*128 + kb) ^ ((row & 7) << 4);
        af[i] = *(const bf16x8*)((const char*)As + ab);
        int col = wc*64 + i*16 + (lane & 15);
        int bb  = (col*128 + kb) ^ ((col & 7) << 4);
        bfr[i] = *(const bf16x8*)((const char*)Bs + bb);
      }
#pragma unroll
      for (int i = 0; i < 4; ++i)
#pragma unroll
        for (int j = 0; j < 4; ++j)
          acc[i][j] = __builtin_amdgcn_mfma_f32_16x16x32_bf16(af[i], bfr[j], acc[i][j], 0, 0, 0);
    }
    __syncthreads();
  }

  // ---- epilogue ----
  float* Cf = (float*)Cv;
  unsigned short* Cb = (unsigned short*)Cv;
#pragma unroll
  for (int j = 0; j < 4; ++j){
    int col = col0 + wc*64 + j*16 + (lane & 15);
    float bs = bias[col];
#pragma unroll
    for (int i = 0; i < 4; ++i){
      int rb = row0 + wr*64 + i*16 + ((lane >> 4) << 2);
#pragma unroll
      for (int r = 0; r < 4; ++r){
        int row = rb + r;
        if (row < M){
          float v = acc[i][j][r] + bs;
          if (RELU) v = fmaxf(v, 0.f);
          if (OUT_BF16) Cb[(size_t)row*ldc + col] = f2bf(v);
          else          Cf[(size_t)row*ldc + col] = v;
        }
      }
    }
  }
}

// ------- conv GEMM: 128x128 tile, K=128 one-shot, fused pre-BN + fused stats -------
// C[M][ldc] = (PRO_BN ? relu(ks*A+kf) : A) @ Bt^T + bias; bf16 out; f32 column stats.
template<bool PRO_BN, bool STATS>
__global__ __launch_bounds__(256) void k_mmc(
    const unsigned short* __restrict__ A,     // [M][128] bf16
    const unsigned short* __restrict__ Bt,    // [128][128] bf16, n-major
    const float* __restrict__ bias,           // [128]
    const float* __restrict__ kscale, const float* __restrict__ kshift,
    unsigned short* __restrict__ C, int ldc,
    float* sums, float* sumsq,
    int M)
{
  __shared__ unsigned short As[128*128];   // 32 KB, 256 B per row
  __shared__ unsigned short Bs[128*128];   // 32 KB
  const int tid  = threadIdx.x;
  const int lane = tid & 63;
  const int w    = tid >> 6;
  const int wr   = w >> 1, wc = w & 1;

  const int wg   = xcd_swz(blockIdx.x, gridDim.x);
  const int row0 = wg * 128;

  // stage whole tiles: wave w owns 8 KB of each array (8 chunks of 1 KB)
#pragma unroll
  for (int j = 0; j < 8; ++j){
    int d = w*8192 + j*1024 + lane*16;
    int m = d >> 8;                            // row (256 B rows)
    int inner = (d & 255) ^ ((m & 15) << 4);   // inverse swizzle
    int gm = row0 + m; if (gm > M-1) gm = M-1;
    __builtin_amdgcn_global_load_lds(
        (const __attribute__((address_space(1))) void*)(A + (size_t)gm*H + (inner >> 1)),
        (__attribute__((address_space(3))) void*)((char*)As + w*8192 + j*1024),
        16, 0, 0);
    __builtin_amdgcn_global_load_lds(
        (const __attribute__((address_space(1))) void*)(Bt + (size_t)m*H + (inner >> 1)),
        (__attribute__((address_space(3))) void*)((char*)Bs + w*8192 + j*1024),
        16, 0, 0);
  }
  asm volatile("s_waitcnt vmcnt(0)" ::: "memory");
  __syncthreads();

  f32x4 acc[4][4];
#pragma unroll
  for (int i = 0; i < 4; ++i)
#pragma unroll
    for (int j = 0; j < 4; ++j)
      acc[i][j] = (f32x4){0.f, 0.f, 0.f, 0.f};

#pragma unroll
  for (int kk = 0; kk < 4; ++kk){
    const int kb = kk*64 + ((lane >> 4) << 4);
    bf16x8 af[4], bfr[4];
#pragma unroll
    for (int i = 0; i < 4; ++i){
      int row = wr*64 + i*16 + (lane & 15);
      int ab  = (row*256 + kb) ^ ((row & 15) << 4);
      af[i] = *(const bf16x8*)((const char*)As + ab);
      int col = wc*64 + i*16 + (lane & 15);
      int bb  = (col*256 + kb) ^ ((col & 15) << 4);
      bfr[i] = *(const bf16x8*)((const char*)Bs + bb);
    }
    if (PRO_BN){
      int k8 = kk*32 + ((lane >> 4) << 3);
      float4 s0 = *(const float4*)(kscale + k8), s1 = *(const float4*)(kscale + k8 + 4);
      float4 f0 = *(const float4*)(kshift + k8), f1 = *(const float4*)(kshift + k8 + 4);
      float sc[8] = {s0.x,s0.y,s0.z,s0.w,s1.x,s1.y,s1.z,s1.w};
      float sf[8] = {f0.x,f0.y,f0.z,f0.w,f1.x,f1.y,f1.z,f1.w};
#pragma unroll
      for (int i = 0; i < 4; ++i){
        bf16x8 a = af[i], o;
#pragma unroll
        for (int j = 0; j < 8; ++j){
          float v = fmaxf(fmaf(sc[j], bf2f((unsigned short)a[j]), sf[j]), 0.f);
          o[j] = (short)f2bf(v);
        }
        af[i] = o;
      }
    }
#pragma unroll
    for (int i = 0; i < 4; ++i)
#pragma unroll
      for (int j = 0; j < 4; ++j)
        acc[i][j] = __builtin_amdgcn_mfma_f32_16x16x32_bf16(af[i], bfr[j], acc[i][j], 0, 0, 0);
  }

  if (STATS){
#pragma unroll
    for (int j = 0; j < 4; ++j){
      int col = wc*64 + j*16 + (lane & 15);
      float bs = bias[col];
      float s = 0.f, q = 0.f;
#pragma unroll
      for (int i = 0; i < 4; ++i){
        int rb = row0 + wr*64 + i*16 + ((lane >> 4) << 2);
#pragma unroll
        for (int r = 0; r < 4; ++r){
          if (rb + r < M){
            float v = acc[i][j][r] + bs;
            s += v; q += v*v;
          }
        }
      }
      s += __shfl_xor(s, 16); q += __shfl_xor(q, 16);
      s += __shfl_xor(s, 32); q += __shfl_xor(q, 32);
      if (lane < 16){
        atomicAdd(&sums[col], s);
        atomicAdd(&sumsq[col], q);
      }
    }
  }

#pragma unroll
  for (int j = 0; j < 4; ++j){
    int col = wc*64 + j*16 + (lane & 15);
    float bs = bias[col];
#pragma unroll
    for (int i = 0; i < 4; ++i){
      int rb = row0 + wr*64 + i*16 + ((lane >> 4) << 2);
#pragma unroll
      for (int r = 0; r < 4; ++r){
        int row = rb + r;
        if (row < M)
          C[(size_t)row*ldc + col] = f2bf(acc[i][j][r] + bs);
      }
    }
  }
}

// ---------------- f32 GEMM 64x64 (graph FF, M=512) ----------------
template<bool RELU, bool ADD_D>
__global__ __launch_bounds__(256) void k_gemm64(
    const float* __restrict__ A, int lda,
    const float* __restrict__ B, int ldb,
    const float* __restrict__ bias,
    const float* D, int ldd,
    float* C, int ldc,
    int M, int N, int K)
{
  __shared__ float As[32][68];
  __shared__ float Bs[32][64];
  const int tid  = threadIdx.x;
  const int tx   = tid & 15;
  const int ty   = tid >> 4;
  const int row0 = blockIdx.x * 64;
  const int col0 = blockIdx.y * 64;
  const int am = tid >> 3;
  const int ak = (tid & 7) << 2;
  const int bk = tid >> 4;
  const int bn = (tid & 15) << 2;
  float acc[4][4] = {};

  for (int k0 = 0; k0 < K; k0 += 32){
#pragma unroll
    for (int h = 0; h < 2; ++h){
      int m  = am + h*32;
      int gr = row0 + m;
      float4 v = make_float4(0.f, 0.f, 0.f, 0.f);
      if (gr < M) v = *(const float4*)(A + (size_t)gr*lda + k0 + ak);
      As[ak+0][m]=v.x; As[ak+1][m]=v.y; As[ak+2][m]=v.z; As[ak+3][m]=v.w;
    }
#pragma unroll
    for (int h = 0; h < 2; ++h){
      int kk = bk + h*16;
      *(float4*)(&Bs[kk][bn]) = *(const float4*)(B + (size_t)(k0+kk)*ldb + col0 + bn);
    }
    __syncthreads();
#pragma unroll 8
    for (int k = 0; k < 32; ++k){
      float4 a = *(const float4*)(&As[k][ty<<2]);
      float4 b = *(const float4*)(&Bs[k][tx<<2]);
      float av[4] = {a.x,a.y,a.z,a.w};
      float bv[4] = {b.x,b.y,b.z,b.w};
#pragma unroll
      for (int i = 0; i < 4; ++i)
#pragma unroll
        for (int j = 0; j < 4; ++j)
          acc[i][j] = fmaf(av[i], bv[j], acc[i][j]);
    }
    __syncthreads();
  }

  const int col = col0 + (tx<<2);
  float4 bv = *(const float4*)(bias + col);
#pragma unroll
  for (int i = 0; i < 4; ++i){
    int row = row0 + (ty<<2) + i;
    if (row < M){
      float r[4] = {acc[i][0]+bv.x, acc[i][1]+bv.y, acc[i][2]+bv.z, acc[i][3]+bv.w};
      if (RELU){
#pragma unroll
        for (int j = 0; j < 4; ++j) r[j] = fmaxf(r[j], 0.f);
      }
      if (ADD_D){
        float4 d = *(const float4*)(D + (size_t)row*ldd + col);
        r[0]+=d.x; r[1]+=d.y; r[2]+=d.z; r[3]+=d.w;
      }
      *(float4*)(C + (size_t)row*ldc + col) = make_float4(r[0],r[1],r[2],r[3]);
    }
  }
}

// ---------------- host ----------------
extern "C" void kernel_launch(void* const* d_in, const int* in_sizes, int n_in,
                              void* d_out, int out_size, void* d_ws, size_t ws_size,
                              hipStream_t stream) {
  const float* x        = (const float*)d_in[0];
  const int*   ei       = (const int*)d_in[1];
  const int*   batch    = (const int*)d_in[2];
  const float* conv_W1  = (const float*)d_in[3];
  const float* conv_b1  = (const float*)d_in[4];
  const float* conv_g1  = (const float*)d_in[5];
  const float* conv_be1 = (const float*)d_in[6];
  const float* conv_W2  = (const float*)d_in[7];
  const float* conv_b2  = (const float*)d_in[8];
  const float* epsv     = (const float*)d_in[9];
  const float* bn_g     = (const float*)d_in[10];
  const float* bn_b     = (const float*)d_in[11];
  const float* pred_W   = (const float*)d_in[12];
  const float* pred_b   = (const float*)d_in[13];
  const float* gW       = (const float*)d_in[14];
  const float* gb       = (const float*)d_in[15];
  const float* gsW      = (const float*)d_in[16];
  const float* gsb      = (const float*)d_in[17];
  const float* lW       = (const float*)d_in[18];
  const float* lb       = (const float*)d_in[19];
  const float* lsW      = (const float*)d_in[20];
  const float* lsb      = (const float*)d_in[21];

  const int N = in_sizes[0] / H;
  const int E = in_sizes[1] / 2;
  const int* srcI = ei;
  const int* dstI = ei + E;

  float* out = (float*)d_out;
  float* GE = out;                              // [NG][EMB]
  float* NE = out + (size_t)NG*EMB;             // [N][EMB] f32
  float* XC = NE + (size_t)N*EMB;               // [NG][EMB]

  // ---- workspace layout ----
  unsigned short* xall = (unsigned short*)d_ws;             // [N][EMB] bf16
  unsigned short* h1   = xall + (size_t)N*EMB;              // [N][EMB] bf16
  unsigned short* h2   = h1 + (size_t)N*EMB;                // [N][EMB] bf16
  // conv-loop aliases inside h1 region (3*N*H < N*EMB)
  unsigned short* hpre = h1;                                // [N][H]
  unsigned short* ub   = h1 + (size_t)N*H;                  // [N][H]
  unsigned short* tb   = h1 + (size_t)2*N*H;                // [N][H]

  float* pooled  = (float*)(h2 + (size_t)N*EMB);            // [NG][EMB]
  float* gtmp1   = pooled + (size_t)NG*EMB;
  float* gtmp2   = gtmp1 + (size_t)NG*EMB;
  float* sums    = gtmp2 + (size_t)NG*EMB;                  // [128]
  float* sumsq   = sums + 128;
  float* bnscale = sumsq + 128;
  float* bnshift = bnscale + 128;
  float* biasNE  = bnshift + 128;                           // [640]
  unsigned short* W1t   = (unsigned short*)(biasNE + EMB);  // [L][H][H]
  unsigned short* W2t   = W1t + (size_t)LNUM*H*H;
  unsigned short* lWt01 = W2t + (size_t)LNUM*H*H;           // [2][EMB][EMB]
  unsigned short* Wcat  = lWt01 + (size_t)2*EMB*EMB;        // [EMB][2*EMB]
  int* rowptr = (int*)(Wcat + (size_t)2*EMB*EMB);           // [N+1]
  int* cursor = rowptr + (N + 1);                           // [N]
  int* colsrc = cursor + N;                                 // [E]
  int* gstart = colsrc + E;                                 // [NG+1]

  // stat accumulators must be zero every call
  k_zerof<<<1, 256, 0, stream>>>(sums, 256);

  // CSR build
  k_zeroi<<<(N+255)/256, 256, 0, stream>>>(cursor, N);
  k_hist<<<(E+255)/256, 256, 0, stream>>>(dstI, E, cursor);
  k_scan<<<1, 1024, 0, stream>>>(cursor, rowptr, N);
  k_scatter<<<(E+255)/256, 256, 0, stream>>>(srcI, dstI, E, cursor, colsrc);
  k_gstart<<<(NG+256)/256, 256, 0, stream>>>(batch, N, gstart);

  // weights -> bf16 transposed [n][k]
  const dim3 tb32(32, 8);
  k_castT<<<dim3(H/32, H/32, LNUM), tb32, 0, stream>>>(conv_W1, W1t, H, H, H, 0);
  k_castT<<<dim3(H/32, H/32, LNUM), tb32, 0, stream>>>(conv_W2, W2t, H, H, H, 0);
  k_castT<<<dim3(EMB/32, EMB/32, 2), tb32, 0, stream>>>(lW, lWt01, EMB, EMB, EMB, 0);
  k_castT<<<dim3(EMB/32, EMB/32, 1), tb32, 0, stream>>>(lW + (size_t)2*EMB*EMB, Wcat,
                                                        EMB, EMB, 2*EMB, 0);
  k_castT<<<dim3(EMB/32, EMB/32, 1), tb32, 0, stream>>>(lsW, Wcat, EMB, EMB, 2*EMB, EMB);
  k_bias2<<<1, EMB, 0, stream>>>(lb + (size_t)2*EMB, lsb, biasNE);

  const float invn = 1.0f / (float)N;
  const int nrow = (N + 127)/128;               // 391

  for (int l = 0; l < LNUM; ++l){
    if (l == 0)
      k_agg<false><<<(N+3)/4, 256, 0, stream>>>(x, H, rowptr, colsrc, epsv, hpre, N);
    else
      k_agg<true><<<(N+3)/4, 256, 0, stream>>>(xall + (size_t)(l-1)*H, EMB, rowptr, colsrc,
                                               epsv + l, hpre, N);

    // u = hpre @ W1 + b1  (bf16 out + stats)
    k_mmc<false,true><<<nrow, 256, 0, stream>>>(
        hpre, W1t + (size_t)l*H*H, conv_b1 + l*H, nullptr, nullptr,
        ub, H, sums, sumsq, N);
    k_bnfin<<<1, 128, 0, stream>>>(sums, sumsq, conv_g1 + l*H, conv_be1 + l*H,
                                   bnscale, bnshift, invn);
    // u2 = relu(bn1(u)) @ W2 + b2  (fused pre-BN on A; bf16 out + stats)
    k_mmc<true,true><<<nrow, 256, 0, stream>>>(
        ub, W2t + (size_t)l*H*H, conv_b2 + l*H, bnscale, bnshift,
        tb, H, sums, sumsq, N);
    k_bnfin<<<1, 128, 0, stream>>>(sums, sumsq, bn_g + l*H, bn_b + l*H,
                                   bnscale, bnshift, invn);
    k_bnapply<<<(N*32 + 255)/256, 256, 0, stream>>>(tb, bnscale, bnshift,
                                                    xall + (size_t)l*H, EMB, N);
  }

  // pooling + per-layer prediction heads -> xcat
  k_pool<<<NG, 320, 0, stream>>>(xall, gstart, pooled);
  k_pred<<<dim3(NG, LNUM), 128, 0, stream>>>(pooled, pred_W, pred_b, XC);

  // graph FF (f32, M=512): GE = relu-chain(XC) + XC @ gsW + gsb
  const dim3 gg((NG + 63)/64, EMB/64);
  k_gemm64<false,false><<<gg, 256, 0, stream>>>(XC, EMB, gsW, EMB, gsb,
                                                nullptr, 0, GE, EMB, NG, EMB, EMB);
  k_gemm64<true,false><<<gg, 256, 0, stream>>>(XC, EMB, gW, EMB, gb,
                                               nullptr, 0, gtmp1, EMB, NG, EMB, EMB);
  k_gemm64<true,false><<<gg, 256, 0, stream>>>(gtmp1, EMB, gW + (size_t)EMB*EMB, EMB, gb + EMB,
                                               nullptr, 0, gtmp2, EMB, NG, EMB, EMB);
  k_gemm64<true,true><<<gg, 256, 0, stream>>>(gtmp2, EMB, gW + (size_t)2*EMB*EMB, EMB, gb + 2*EMB,
                                              GE, EMB, GE, EMB, NG, EMB, EMB);

  // node FF (bf16 MFMA, col-fast grid + XCD swizzle):
  const dim3 gn(EMB/128, nrow);                 // (5, 391)
  // h1 = relu(xall @ lW0 + lb0)
  k_mm<true,true,false><<<gn, 256, 0, stream>>>(
      xall, EMB, nullptr, lWt01, EMB, lb, h1, EMB, N, EMB);
  // h2 = relu(h1 @ lW1 + lb1)
  k_mm<true,true,false><<<gn, 256, 0, stream>>>(
      h1, EMB, nullptr, lWt01 + (size_t)EMB*EMB, EMB, lb + EMB, h2, EMB, N, EMB);
  // NE = [h2 | xall] @ [lW2 ; lsW] + (lb2 + lsb)   (dual-A, K=1280, f32 out)
  k_mm<false,false,true><<<gn, 256, 0, stream>>>(
      h2, EMB, xall, Wcat, 2*EMB, biasNE, NE, EMB, N, 2*EMB);
}

// Round 5
// 1423.655 us; speedup vs baseline: 2.3982x; 1.0962x over previous
//
#include <hip/hip_runtime.h>

constexpr int H    = 128;
constexpr int LNUM = 5;
constexpr int NG   = 512;
constexpr int EMB  = 640;   // LNUM * H
constexpr float BN_EPS = 1e-5f;

typedef __attribute__((ext_vector_type(8))) short bf16x8;
typedef __attribute__((ext_vector_type(4))) float f32x4;

__device__ inline unsigned short f2bf(float f){
  unsigned u = __builtin_bit_cast(unsigned, f);
  u += 0x7FFF + ((u >> 16) & 1);
  return (unsigned short)(u >> 16);
}
__device__ inline float bf2f(unsigned short h){
  unsigned u = ((unsigned)h) << 16;
  return __builtin_bit_cast(float, u);
}

// bijective XCD chunk swizzle (m204)
__device__ inline int xcd_swz(int bid, int nwg){
  int q = nwg >> 3, r = nwg & 7;
  int xcd = bid & 7, idx = bid >> 3;
  return (xcd < r ? xcd*(q+1) : r*(q+1) + (xcd-r)*q) + idx;
}

// ---------------- utility ----------------
__global__ void k_zerof(float* p, int n){
  int i = blockIdx.x*256 + threadIdx.x;
  if (i < n) p[i] = 0.f;
}
__global__ void k_zeroi(int* p, int n){
  int i = blockIdx.x*256 + threadIdx.x;
  if (i < n) p[i] = 0;
}

// ---------------- CSR build ----------------
__global__ void k_hist(const int* __restrict__ dst, int E, int* deg){
  int e = blockIdx.x*256 + threadIdx.x;
  if (e < E) atomicAdd(&deg[dst[e]], 1);
}

// shfl-based block scan: degcur -> exclusive cursor, rowptr[i+1] = inclusive
__global__ __launch_bounds__(1024) void k_scan(int* degcur, int* __restrict__ rowptr, int n){
  __shared__ int wsum[16];
  __shared__ int carry;
  int tid = threadIdx.x, wid = tid >> 6, lane = tid & 63;
  if (tid == 0){ carry = 0; rowptr[0] = 0; }
  __syncthreads();
  for (int base = 0; base < n; base += 1024){
    int v = (base + tid < n) ? degcur[base + tid] : 0;
    int s = v;
#pragma unroll
    for (int off = 1; off < 64; off <<= 1){
      int t = __shfl_up(s, off);
      if (lane >= off) s += t;
    }
    if (lane == 63) wsum[wid] = s;
    __syncthreads();
    if (wid == 0 && lane < 16){
      int wv = wsum[lane];
#pragma unroll
      for (int off = 1; off < 16; off <<= 1){
        int t = __shfl_up(wv, off);
        if (lane >= off) wv += t;
      }
      wsum[lane] = wv;
    }
    __syncthreads();
    int incl = s + (wid ? wsum[wid-1] : 0) + carry;
    if (base + tid < n){ rowptr[base + tid + 1] = incl; degcur[base + tid] = incl - v; }
    __syncthreads();
    if (tid == 0) carry += wsum[15];
    __syncthreads();
  }
}

__global__ void k_scatter(const int* __restrict__ src, const int* __restrict__ dst,
                          int E, int* cursor, int* __restrict__ colsrc){
  int e = blockIdx.x*256 + threadIdx.x;
  if (e < E){
    int d = dst[e];
    int pos = atomicAdd(&cursor[d], 1);
    colsrc[pos] = src[e];
  }
}

__global__ void k_gstart(const int* __restrict__ batch, int N, int* __restrict__ gstart){
  int g = blockIdx.x*256 + threadIdx.x;
  if (g <= NG){
    int lo = 0, hi = N;
    while (lo < hi){
      int mid = (lo + hi) >> 1;
      if (batch[mid] < g) lo = mid + 1; else hi = mid;
    }
    gstart[g] = lo;
  }
}

// ---- weight cast+transpose: W[k][n] f32 -> Wt[n][ldt] bf16 at column offset koff ----
__global__ void k_castT(const float* __restrict__ W, unsigned short* __restrict__ Wt,
                        int K, int Nn, int ldt, int koff){
  __shared__ float sh[32][33];
  const size_t in_off  = (size_t)blockIdx.z * K * Nn;
  const size_t out_off = (size_t)blockIdx.z * Nn * ldt;
  int n0 = blockIdx.x*32, k0 = blockIdx.y*32;
  int tx = threadIdx.x, ty = threadIdx.y;   // 32 x 8
  for (int r = ty; r < 32; r += 8)
    sh[r][tx] = W[in_off + (size_t)(k0 + r)*Nn + n0 + tx];
  __syncthreads();
  for (int r = ty; r < 32; r += 8)
    Wt[out_off + (size_t)(n0 + r)*ldt + koff + k0 + tx] = f2bf(sh[tx][r]);
}

__global__ void k_bias2(const float* __restrict__ a, const float* __restrict__ b,
                        float* __restrict__ o){
  int i = threadIdx.x;
  o[i] = a[i] + b[i];
}

// ------- GIN aggregation: wave per node, lane handles 2 feats via u32 -------
template<bool IN_BF16>
__global__ __launch_bounds__(256) void k_agg(const void* __restrict__ hin_, int ldh,
                                             const int* __restrict__ rowptr,
                                             const int* __restrict__ colsrc,
                                             const float* __restrict__ epsp,
                                             unsigned short* __restrict__ outp, int nN){
  int node = blockIdx.x*4 + (threadIdx.x >> 6);
  if (node >= nN) return;
  int lane = threadIdx.x & 63;
  float a0, a1;
  if (IN_BF16){
    unsigned u = ((const unsigned*)hin_)[((size_t)node*ldh >> 1) + lane];
    a0 = bf2f((unsigned short)u); a1 = bf2f((unsigned short)(u >> 16));
  } else {
    float2 f = ((const float2*)hin_)[((size_t)node*ldh >> 1) + lane];
    a0 = f.x; a1 = f.y;
  }
  float ep = 1.0f + *epsp;
  a0 *= ep; a1 *= ep;
  int e1 = rowptr[node+1];
  for (int e = rowptr[node]; e < e1; ++e){
    int s = colsrc[e];
    if (IN_BF16){
      unsigned u = ((const unsigned*)hin_)[((size_t)s*ldh >> 1) + lane];
      a0 += bf2f((unsigned short)u); a1 += bf2f((unsigned short)(u >> 16));
    } else {
      float2 f = ((const float2*)hin_)[((size_t)s*ldh >> 1) + lane];
      a0 += f.x; a1 += f.y;
    }
  }
  ((unsigned*)outp)[((size_t)node*H >> 1) + lane] =
      (unsigned)f2bf(a0) | ((unsigned)f2bf(a1) << 16);
}

// ---------------- BN finalize ----------------
__global__ void k_bnfin(float* sums, float* sumsq,
                        const float* __restrict__ g, const float* __restrict__ b,
                        float* __restrict__ scale, float* __restrict__ shift, float invn){
  int c = threadIdx.x;
  float m = sums[c]*invn;
  float v = sumsq[c]*invn - m*m;
  float inv = rsqrtf(v + BN_EPS);
  float sc = g[c]*inv;
  scale[c] = sc;
  shift[c] = b[c] - m*sc;
  sums[c] = 0.f; sumsq[c] = 0.f;
}

// out[r][c] = bf16(relu(scale[c]*bf2f(U[r][c]) + shift[c])), out leading-dim ldo
__global__ __launch_bounds__(256) void k_bnapply(const unsigned short* __restrict__ U,
                                                 const float* __restrict__ scale,
                                                 const float* __restrict__ shift,
                                                 unsigned short* __restrict__ out,
                                                 int ldo, int n){
  int i = blockIdx.x*256 + threadIdx.x;
  int total = n * (H/4);
  if (i < total){
    int r = i >> 5;
    int c4 = (i & 31) << 2;
    uint2 up = *(const uint2*)(U + (size_t)r*H + c4);
    float4 sc = *(const float4*)(scale + c4);
    float4 sf = *(const float4*)(shift + c4);
    float a = fmaxf(fmaf(sc.x, bf2f((unsigned short)up.x),        sf.x), 0.f);
    float b = fmaxf(fmaf(sc.y, bf2f((unsigned short)(up.x>>16)),  sf.y), 0.f);
    float c = fmaxf(fmaf(sc.z, bf2f((unsigned short)up.y),        sf.z), 0.f);
    float d = fmaxf(fmaf(sc.w, bf2f((unsigned short)(up.y>>16)),  sf.w), 0.f);
    uint2 o;
    o.x = (unsigned)f2bf(a) | ((unsigned)f2bf(b) << 16);
    o.y = (unsigned)f2bf(c) | ((unsigned)f2bf(d) << 16);
    *(uint2*)(out + (size_t)r*ldo + c4) = o;
  }
}

// ---------------- pooling + prediction heads ----------------
__global__ __launch_bounds__(320) void k_pool(const unsigned short* __restrict__ xall,
                                              const int* __restrict__ gstart,
                                              float* __restrict__ pooled){
  int g = blockIdx.x;
  int t = threadIdx.x;
  int n0 = gstart[g], n1 = gstart[g+1];
  float a0 = 0.f, a1 = 0.f;
  for (int n = n0; n < n1; ++n){
    unsigned u = ((const unsigned*)xall)[(size_t)n*(EMB/2) + t];
    a0 += bf2f((unsigned short)u); a1 += bf2f((unsigned short)(u >> 16));
  }
  *(float2*)(pooled + (size_t)g*EMB + 2*t) = make_float2(a0, a1);
}

__global__ __launch_bounds__(128) void k_pred(const float* __restrict__ pooled,
                                              const float* __restrict__ W,
                                              const float* __restrict__ b,
                                              float* __restrict__ xcat){
  int g = blockIdx.x, l = blockIdx.y, o = threadIdx.x;
  __shared__ float sh[128];
  sh[o] = pooled[(size_t)g*EMB + l*H + o];
  __syncthreads();
  const float* Wl = W + (size_t)l*H*H;
  float acc = b[l*H + o];
  for (int k = 0; k < H; ++k) acc = fmaf(sh[k], Wl[k*H + o], acc);
  xcat[(size_t)g*EMB + l*H + o] = acc;
}

// ---------------- bf16 MFMA GEMM, 128x128 tile, BK=64 ----------------
// depth-2 pipeline with counted vmcnt(8); LDS-transpose coalesced epilogue.
// DUAL: A rows are [A | A2] concatenated along K (each K/2 wide).
template<bool RELU, bool OUT_BF16, bool DUAL>
__global__ __launch_bounds__(256) void k_mm(
    const unsigned short* __restrict__ A, int lda,
    const unsigned short* __restrict__ A2,
    const unsigned short* __restrict__ Bt, int ldb,
    const float* __restrict__ bias,
    void* __restrict__ Cv, int ldc,
    int M, int K)
{
  __shared__ union LdsU {
    unsigned short stage[2][2][128*64];   // [buf][A/B] 64 KB
    unsigned short sc16[128*136];         // 34 KB epilogue scratch (bf16)
    float          sc32[128*132];         // 66 KB epilogue scratch (f32)
  } u;
  const int tid  = threadIdx.x;
  const int lane = tid & 63;
  const int w    = tid >> 6;
  const int wr   = w >> 1, wc = w & 1;

  const int nwg = gridDim.x * gridDim.y;
  const int bid = blockIdx.y * gridDim.x + blockIdx.x;
  const int wg  = xcd_swz(bid, nwg);
  const int col0 = (wg % gridDim.x) * 128;
  const int row0 = (wg / gridDim.x) * 128;
  const int KA   = DUAL ? (K >> 1) : K;

  // staging sources: wave w owns LDS bytes [w*4K, w*4K+4K) per tile, 4 chunks of 1KB
  const unsigned short *sA[4], *sA2[4], *sB[4];
  int dOff[4];
#pragma unroll
  for (int j = 0; j < 4; ++j){
    int d = w*4096 + j*1024 + lane*16;        // linear LDS byte dest
    int m = d >> 7;                           // tile row of this dest
    int inner = (d & 127) ^ ((m & 7) << 4);   // inverse-swizzled byte-in-row
    int gm = row0 + m; if (gm > M-1) gm = M-1;
    sA[j]  = A  + (size_t)gm*lda + (inner >> 1);
    if (DUAL) sA2[j] = A2 + (size_t)gm*lda + (inner >> 1);
    sB[j]  = Bt + (size_t)(col0 + m)*ldb + (inner >> 1);
    dOff[j] = w*4096 + j*1024;
  }

  f32x4 acc[4][4];
#pragma unroll
  for (int i = 0; i < 4; ++i)
#pragma unroll
    for (int j = 0; j < 4; ++j)
      acc[i][j] = (f32x4){0.f, 0.f, 0.f, 0.f};

  auto STAGE = [&](int buf, int kt){            // 8 loads per wave
    int k0 = kt*64;
    int ka = k0;
    bool second = DUAL && (k0 >= KA);
    if (second) ka = k0 - KA;
#pragma unroll
    for (int j = 0; j < 4; ++j){
      const unsigned short* srcA = second ? (sA2[j] + ka) : (sA[j] + ka);
      __builtin_amdgcn_global_load_lds(
          (const __attribute__((address_space(1))) void*)srcA,
          (__attribute__((address_space(3))) void*)((char*)&u.stage[buf][0][0] + dOff[j]),
          16, 0, 0);
    }
#pragma unroll
    for (int j = 0; j < 4; ++j)
      __builtin_amdgcn_global_load_lds(
          (const __attribute__((address_space(1))) void*)(sB[j] + k0),
          (__attribute__((address_space(3))) void*)((char*)&u.stage[buf][1][0] + dOff[j]),
          16, 0, 0);
  };

  auto COMPUTE = [&](int buf){
    const char* Ab = (const char*)&u.stage[buf][0][0];
    const char* Bb = (const char*)&u.stage[buf][1][0];
#pragma unroll
    for (int kk = 0; kk < 2; ++kk){
      const int kb = kk*64 + ((lane >> 4) << 4);
      bf16x8 af[4], bfr[4];
#pragma unroll
      for (int i = 0; i < 4; ++i){
        int row = wr*64 + i*16 + (lane & 15);
        int ab  = (row*128 + kb) ^ ((row & 7) << 4);
        af[i] = *(const bf16x8*)(Ab + ab);
        int col = wc*64 + i*16 + (lane & 15);
        int bb  = (col*128 + kb) ^ ((col & 7) << 4);
        bfr[i] = *(const bf16x8*)(Bb + bb);
      }
#pragma unroll
      for (int i = 0; i < 4; ++i)
#pragma unroll
        for (int j = 0; j < 4; ++j)
          acc[i][j] = __builtin_amdgcn_mfma_f32_16x16x32_bf16(af[i], bfr[j], acc[i][j], 0, 0, 0);
    }
  };

  const int NT = K / 64;   // >= 2 for all uses
  STAGE(0, 0);
  STAGE(1, 1);
  asm volatile("s_waitcnt vmcnt(8)" ::: "memory");   // tile 0 landed
  __syncthreads();

  int cur = 0;
  for (int t = 0; t < NT; ++t){
    COMPUTE(cur);
    if (t == NT-1) break;
    __syncthreads();                                 // all waves done reading buf cur
    if (t + 2 < NT){
      STAGE(cur, t + 2);                             // 8 new loads
      asm volatile("s_waitcnt vmcnt(8)" ::: "memory"); // tile t+1 landed, t+2 in flight
    } else {
      asm volatile("s_waitcnt vmcnt(0)" ::: "memory"); // final tile landed
    }
    __syncthreads();
    cur ^= 1;
  }

  // ---- epilogue: transpose via LDS, coalesced stream-out ----
  __syncthreads();   // staging buffers now dead
  if (OUT_BF16){
#pragma unroll
    for (int j = 0; j < 4; ++j){
      int cl = wc*64 + j*16 + (lane & 15);
      float bs = bias[col0 + cl];
#pragma unroll
      for (int i = 0; i < 4; ++i){
        int rb = wr*64 + i*16 + ((lane >> 4) << 2);
#pragma unroll
        for (int r = 0; r < 4; ++r){
          float v = acc[i][j][r] + bs;
          if (RELU) v = fmaxf(v, 0.f);
          u.sc16[(rb + r)*136 + cl] = f2bf(v);
        }
      }
    }
    __syncthreads();
    unsigned short* Cb = (unsigned short*)Cv;
    for (int idx = tid; idx < 128*16; idx += 256){
      int rr = idx >> 4, seg = idx & 15;
      int grow = row0 + rr;
      if (grow < M){
        uint4 vv = *(const uint4*)&u.sc16[rr*136 + seg*8];
        *(uint4*)(Cb + (size_t)grow*ldc + col0 + seg*8) = vv;
      }
    }
  } else {
#pragma unroll
    for (int j = 0; j < 4; ++j){
      int cl = wc*64 + j*16 + (lane & 15);
      float bs = bias[col0 + cl];
#pragma unroll
      for (int i = 0; i < 4; ++i){
        int rb = wr*64 + i*16 + ((lane >> 4) << 2);
#pragma unroll
        for (int r = 0; r < 4; ++r){
          float v = acc[i][j][r] + bs;
          if (RELU) v = fmaxf(v, 0.f);
          u.sc32[(rb + r)*132 + cl] = v;
        }
      }
    }
    __syncthreads();
    float* Cf = (float*)Cv;
    for (int idx = tid; idx < 128*32; idx += 256){
      int rr = idx >> 5, seg = idx & 31;
      int grow = row0 + rr;
      if (grow < M){
        float4 vv = *(const float4*)&u.sc32[rr*132 + seg*4];
        *(float4*)(Cf + (size_t)grow*ldc + col0 + seg*4) = vv;
      }
    }
  }
}

// ------- conv GEMM: 128x128 tile, K=128 one-shot, fused pre-BN + fused stats -------
template<bool PRO_BN, bool STATS>
__global__ __launch_bounds__(256) void k_mmc(
    const unsigned short* __restrict__ A,     // [M][128] bf16
    const unsigned short* __restrict__ Bt,    // [128][128] bf16, n-major
    const float* __restrict__ bias,           // [128]
    const float* __restrict__ kscale, const float* __restrict__ kshift,
    unsigned short* __restrict__ C, int ldc,
    float* sums, float* sumsq,
    int M)
{
  __shared__ unsigned short shm[2*128*128];   // 64 KB: As | Bs; epilogue reuses as [128][136]
  unsigned short* As = shm;
  unsigned short* Bs = shm + 128*128;
  const int tid  = threadIdx.x;
  const int lane = tid & 63;
  const int w    = tid >> 6;
  const int wr   = w >> 1, wc = w & 1;

  const int wg   = xcd_swz(blockIdx.x, gridDim.x);
  const int row0 = wg * 128;

#pragma unroll
  for (int j = 0; j < 8; ++j){
    int d = w*8192 + j*1024 + lane*16;
    int m = d >> 8;                            // row (256 B rows)
    int inner = (d & 255) ^ ((m & 15) << 4);   // inverse swizzle
    int gm = row0 + m; if (gm > M-1) gm = M-1;
    __builtin_amdgcn_global_load_lds(
        (const __attribute__((address_space(1))) void*)(A + (size_t)gm*H + (inner >> 1)),
        (__attribute__((address_space(3))) void*)((char*)As + w*8192 + j*1024),
        16, 0, 0);
    __builtin_amdgcn_global_load_lds(
        (const __attribute__((address_space(1))) void*)(Bt + (size_t)m*H + (inner >> 1)),
        (__attribute__((address_space(3))) void*)((char*)Bs + w*8192 + j*1024),
        16, 0, 0);
  }
  asm volatile("s_waitcnt vmcnt(0)" ::: "memory");
  __syncthreads();

  f32x4 acc[4][4];
#pragma unroll
  for (int i = 0; i < 4; ++i)
#pragma unroll
    for (int j = 0; j < 4; ++j)
      acc[i][j] = (f32x4){0.f, 0.f, 0.f, 0.f};

#pragma unroll
  for (int kk = 0; kk < 4; ++kk){
    const int kb = kk*64 + ((lane >> 4) << 4);
    bf16x8 af[4], bfr[4];
#pragma unroll
    for (int i = 0; i < 4; ++i){
      int row = wr*64 + i*16 + (lane & 15);
      int ab  = (row*256 + kb) ^ ((row & 15) << 4);
      af[i] = *(const bf16x8*)((const char*)As + ab);
      int col = wc*64 + i*16 + (lane & 15);
      int bb  = (col*256 + kb) ^ ((col & 15) << 4);
      bfr[i] = *(const bf16x8*)((const char*)Bs + bb);
    }
    if (PRO_BN){
      int k8 = kk*32 + ((lane >> 4) << 3);
      float4 s0 = *(const float4*)(kscale + k8), s1 = *(const float4*)(kscale + k8 + 4);
      float4 f0 = *(const float4*)(kshift + k8), f1 = *(const float4*)(kshift + k8 + 4);
      float sc[8] = {s0.x,s0.y,s0.z,s0.w,s1.x,s1.y,s1.z,s1.w};
      float sf[8] = {f0.x,f0.y,f0.z,f0.w,f1.x,f1.y,f1.z,f1.w};
#pragma unroll
      for (int i = 0; i < 4; ++i){
        bf16x8 a = af[i], o;
#pragma unroll
        for (int jj = 0; jj < 8; ++jj){
          float v = fmaxf(fmaf(sc[jj], bf2f((unsigned short)a[jj]), sf[jj]), 0.f);
          o[jj] = (short)f2bf(v);
        }
        af[i] = o;
      }
    }
#pragma unroll
    for (int i = 0; i < 4; ++i)
#pragma unroll
      for (int j = 0; j < 4; ++j)
        acc[i][j] = __builtin_amdgcn_mfma_f32_16x16x32_bf16(af[i], bfr[j], acc[i][j], 0, 0, 0);
  }

  if (STATS){
#pragma unroll
    for (int j = 0; j < 4; ++j){
      int col = wc*64 + j*16 + (lane & 15);
      float bs = bias[col];
      float s = 0.f, q = 0.f;
#pragma unroll
      for (int i = 0; i < 4; ++i){
        int rb = row0 + wr*64 + i*16 + ((lane >> 4) << 2);
#pragma unroll
        for (int r = 0; r < 4; ++r){
          if (rb + r < M){
            float v = acc[i][j][r] + bs;
            s += v; q += v*v;
          }
        }
      }
      s += __shfl_xor(s, 16); q += __shfl_xor(q, 16);
      s += __shfl_xor(s, 32); q += __shfl_xor(q, 32);
      if (lane < 16){
        atomicAdd(&sums[col], s);
        atomicAdd(&sumsq[col], q);
      }
    }
  }

  // epilogue: transpose via LDS (staging dead), coalesced 16-B stores
  __syncthreads();
#pragma unroll
  for (int j = 0; j < 4; ++j){
    int cl = wc*64 + j*16 + (lane & 15);
    float bs = bias[cl];
#pragma unroll
    for (int i = 0; i < 4; ++i){
      int rb = wr*64 + i*16 + ((lane >> 4) << 2);
#pragma unroll
      for (int r = 0; r < 4; ++r)
        shm[(rb + r)*136 + cl] = f2bf(acc[i][j][r] + bs);
    }
  }
  __syncthreads();
  for (int idx = tid; idx < 128*16; idx += 256){
    int rr = idx >> 4, seg = idx & 15;
    int grow = row0 + rr;
    if (grow < M){
      uint4 vv = *(const uint4*)&shm[rr*136 + seg*8];
      *(uint4*)(C + (size_t)grow*ldc + seg*8) = vv;
    }
  }
}

// ---------------- f32 GEMM 64x64 (graph FF, M=512) ----------------
template<bool RELU, bool ADD_D>
__global__ __launch_bounds__(256) void k_gemm64(
    const float* __restrict__ A, int lda,
    const float* __restrict__ B, int ldb,
    const float* __restrict__ bias,
    const float* D, int ldd,
    float* C, int ldc,
    int M, int N, int K)
{
  __shared__ float As[32][68];
  __shared__ float Bs[32][64];
  const int tid  = threadIdx.x;
  const int tx   = tid & 15;
  const int ty   = tid >> 4;
  const int row0 = blockIdx.x * 64;
  const int col0 = blockIdx.y * 64;
  const int am = tid >> 3;
  const int ak = (tid & 7) << 2;
  const int bk = tid >> 4;
  const int bn = (tid & 15) << 2;
  float acc[4][4] = {};

  for (int k0 = 0; k0 < K; k0 += 32){
#pragma unroll
    for (int h = 0; h < 2; ++h){
      int m  = am + h*32;
      int gr = row0 + m;
      float4 v = make_float4(0.f, 0.f, 0.f, 0.f);
      if (gr < M) v = *(const float4*)(A + (size_t)gr*lda + k0 + ak);
      As[ak+0][m]=v.x; As[ak+1][m]=v.y; As[ak+2][m]=v.z; As[ak+3][m]=v.w;
    }
#pragma unroll
    for (int h = 0; h < 2; ++h){
      int kk = bk + h*16;
      *(float4*)(&Bs[kk][bn]) = *(const float4*)(B + (size_t)(k0+kk)*ldb + col0 + bn);
    }
    __syncthreads();
#pragma unroll 8
    for (int k = 0; k < 32; ++k){
      float4 a = *(const float4*)(&As[k][ty<<2]);
      float4 b = *(const float4*)(&Bs[k][tx<<2]);
      float av[4] = {a.x,a.y,a.z,a.w};
      float bv[4] = {b.x,b.y,b.z,b.w};
#pragma unroll
      for (int i = 0; i < 4; ++i)
#pragma unroll
        for (int j = 0; j < 4; ++j)
          acc[i][j] = fmaf(av[i], bv[j], acc[i][j]);
    }
    __syncthreads();
  }

  const int col = col0 + (tx<<2);
  float4 bv = *(const float4*)(bias + col);
#pragma unroll
  for (int i = 0; i < 4; ++i){
    int row = row0 + (ty<<2) + i;
    if (row < M){
      float r[4] = {acc[i][0]+bv.x, acc[i][1]+bv.y, acc[i][2]+bv.z, acc[i][3]+bv.w};
      if (RELU){
#pragma unroll
        for (int j = 0; j < 4; ++j) r[j] = fmaxf(r[j], 0.f);
      }
      if (ADD_D){
        float4 d = *(const float4*)(D + (size_t)row*ldd + col);
        r[0]+=d.x; r[1]+=d.y; r[2]+=d.z; r[3]+=d.w;
      }
      *(float4*)(C + (size_t)row*ldc + col) = make_float4(r[0],r[1],r[2],r[3]);
    }
  }
}

// ---------------- host ----------------
extern "C" void kernel_launch(void* const* d_in, const int* in_sizes, int n_in,
                              void* d_out, int out_size, void* d_ws, size_t ws_size,
                              hipStream_t stream) {
  const float* x        = (const float*)d_in[0];
  const int*   ei       = (const int*)d_in[1];
  const int*   batch    = (const int*)d_in[2];
  const float* conv_W1  = (const float*)d_in[3];
  const float* conv_b1  = (const float*)d_in[4];
  const float* conv_g1  = (const float*)d_in[5];
  const float* conv_be1 = (const float*)d_in[6];
  const float* conv_W2  = (const float*)d_in[7];
  const float* conv_b2  = (const float*)d_in[8];
  const float* epsv     = (const float*)d_in[9];
  const float* bn_g     = (const float*)d_in[10];
  const float* bn_b     = (const float*)d_in[11];
  const float* pred_W   = (const float*)d_in[12];
  const float* pred_b   = (const float*)d_in[13];
  const float* gW       = (const float*)d_in[14];
  const float* gb       = (const float*)d_in[15];
  const float* gsW      = (const float*)d_in[16];
  const float* gsb      = (const float*)d_in[17];
  const float* lW       = (const float*)d_in[18];
  const float* lb       = (const float*)d_in[19];
  const float* lsW      = (const float*)d_in[20];
  const float* lsb      = (const float*)d_in[21];

  const int N = in_sizes[0] / H;
  const int E = in_sizes[1] / 2;
  const int* srcI = ei;
  const int* dstI = ei + E;

  float* out = (float*)d_out;
  float* GE = out;                              // [NG][EMB]
  float* NE = out + (size_t)NG*EMB;             // [N][EMB] f32
  float* XC = NE + (size_t)N*EMB;               // [NG][EMB]

  // ---- workspace layout ----
  unsigned short* xall = (unsigned short*)d_ws;             // [N][EMB] bf16
  unsigned short* h1   = xall + (size_t)N*EMB;              // [N][EMB] bf16
  unsigned short* h2   = h1 + (size_t)N*EMB;                // [N][EMB] bf16
  // conv-loop aliases inside h1 region (3*N*H < N*EMB)
  unsigned short* hpre = h1;                                // [N][H]
  unsigned short* ub   = h1 + (size_t)N*H;                  // [N][H]
  unsigned short* tb   = h1 + (size_t)2*N*H;                // [N][H]

  float* pooled  = (float*)(h2 + (size_t)N*EMB);            // [NG][EMB]
  float* gtmp1   = pooled + (size_t)NG*EMB;
  float* gtmp2   = gtmp1 + (size_t)NG*EMB;
  float* sums    = gtmp2 + (size_t)NG*EMB;                  // [128]
  float* sumsq   = sums + 128;
  float* bnscale = sumsq + 128;
  float* bnshift = bnscale + 128;
  float* biasNE  = bnshift + 128;                           // [640]
  unsigned short* W1t   = (unsigned short*)(biasNE + EMB);  // [L][H][H]
  unsigned short* W2t   = W1t + (size_t)LNUM*H*H;
  unsigned short* lWt01 = W2t + (size_t)LNUM*H*H;           // [2][EMB][EMB]
  unsigned short* Wcat  = lWt01 + (size_t)2*EMB*EMB;        // [EMB][2*EMB]
  int* rowptr = (int*)(Wcat + (size_t)2*EMB*EMB);           // [N+1]
  int* cursor = rowptr + (N + 1);                           // [N]
  int* colsrc = cursor + N;                                 // [E]
  int* gstart = colsrc + E;                                 // [NG+1]

  // stat accumulators must be zero every call
  k_zerof<<<1, 256, 0, stream>>>(sums, 256);

  // CSR build
  k_zeroi<<<(N+255)/256, 256, 0, stream>>>(cursor, N);
  k_hist<<<(E+255)/256, 256, 0, stream>>>(dstI, E, cursor);
  k_scan<<<1, 1024, 0, stream>>>(cursor, rowptr, N);
  k_scatter<<<(E+255)/256, 256, 0, stream>>>(srcI, dstI, E, cursor, colsrc);
  k_gstart<<<(NG+256)/256, 256, 0, stream>>>(batch, N, gstart);

  // weights -> bf16 transposed [n][k]
  const dim3 tb32(32, 8);
  k_castT<<<dim3(H/32, H/32, LNUM), tb32, 0, stream>>>(conv_W1, W1t, H, H, H, 0);
  k_castT<<<dim3(H/32, H/32, LNUM), tb32, 0, stream>>>(conv_W2, W2t, H, H, H, 0);
  k_castT<<<dim3(EMB/32, EMB/32, 2), tb32, 0, stream>>>(lW, lWt01, EMB, EMB, EMB, 0);
  k_castT<<<dim3(EMB/32, EMB/32, 1), tb32, 0, stream>>>(lW + (size_t)2*EMB*EMB, Wcat,
                                                        EMB, EMB, 2*EMB, 0);
  k_castT<<<dim3(EMB/32, EMB/32, 1), tb32, 0, stream>>>(lsW, Wcat, EMB, EMB, 2*EMB, EMB);
  k_bias2<<<1, EMB, 0, stream>>>(lb + (size_t)2*EMB, lsb, biasNE);

  const float invn = 1.0f / (float)N;
  const int nrow = (N + 127)/128;               // 391

  for (int l = 0; l < LNUM; ++l){
    if (l == 0)
      k_agg<false><<<(N+3)/4, 256, 0, stream>>>(x, H, rowptr, colsrc, epsv, hpre, N);
    else
      k_agg<true><<<(N+3)/4, 256, 0, stream>>>(xall + (size_t)(l-1)*H, EMB, rowptr, colsrc,
                                               epsv + l, hpre, N);

    // u = hpre @ W1 + b1  (bf16 out + stats)
    k_mmc<false,true><<<nrow, 256, 0, stream>>>(
        hpre, W1t + (size_t)l*H*H, conv_b1 + l*H, nullptr, nullptr,
        ub, H, sums, sumsq, N);
    k_bnfin<<<1, 128, 0, stream>>>(sums, sumsq, conv_g1 + l*H, conv_be1 + l*H,
                                   bnscale, bnshift, invn);
    // u2 = relu(bn1(u)) @ W2 + b2  (fused pre-BN on A; bf16 out + stats)
    k_mmc<true,true><<<nrow, 256, 0, stream>>>(
        ub, W2t + (size_t)l*H*H, conv_b2 + l*H, bnscale, bnshift,
        tb, H, sums, sumsq, N);
    k_bnfin<<<1, 128, 0, stream>>>(sums, sumsq, bn_g + l*H, bn_b + l*H,
                                   bnscale, bnshift, invn);
    k_bnapply<<<(N*32 + 255)/256, 256, 0, stream>>>(tb, bnscale, bnshift,
                                                    xall + (size_t)l*H, EMB, N);
  }

  // pooling + per-layer prediction heads -> xcat
  k_pool<<<NG, 320, 0, stream>>>(xall, gstart, pooled);
  k_pred<<<dim3(NG, LNUM), 128, 0, stream>>>(pooled, pred_W, pred_b, XC);

  // graph FF (f32, M=512): GE = relu-chain(XC) + XC @ gsW + gsb
  const dim3 gg((NG + 63)/64, EMB/64);
  k_gemm64<false,false><<<gg, 256, 0, stream>>>(XC, EMB, gsW, EMB, gsb,
                                                nullptr, 0, GE, EMB, NG, EMB, EMB);
  k_gemm64<true,false><<<gg, 256, 0, stream>>>(XC, EMB, gW, EMB, gb,
                                               nullptr, 0, gtmp1, EMB, NG, EMB, EMB);
  k_gemm64<true,false><<<gg, 256, 0, stream>>>(gtmp1, EMB, gW + (size_t)EMB*EMB, EMB, gb + EMB,
                                               nullptr, 0, gtmp2, EMB, NG, EMB, EMB);
  k_gemm64<true,true><<<gg, 256, 0, stream>>>(gtmp2, EMB, gW + (size_t)2*EMB*EMB, EMB, gb + 2*EMB,
                                              GE, EMB, GE, EMB, NG, EMB, EMB);

  // node FF (bf16 MFMA, col-fast grid + XCD swizzle):
  const dim3 gn(EMB/128, nrow);                 // (5, 391)
  // h1 = relu(xall @ lW0 + lb0)
  k_mm<true,true,false><<<gn, 256, 0, stream>>>(
      xall, EMB, nullptr, lWt01, EMB, lb, h1, EMB, N, EMB);
  // h2 = relu(h1 @ lW1 + lb1)
  k_mm<true,true,false><<<gn, 256, 0, stream>>>(
      h1, EMB, nullptr, lWt01 + (size_t)EMB*EMB, EMB, lb + EMB, h2, EMB, N, EMB);
  // NE = [h2 | xall] @ [lW2 ; lsW] + (lb2 + lsb)   (dual-A, K=1280, f32 out)
  k_mm<false,false,true><<<gn, 256, 0, stream>>>(
      h2, EMB, xall, Wcat, 2*EMB, biasNE, NE, EMB, N, 2*EMB);
}

// Round 6
// 1181.340 us; speedup vs baseline: 2.8902x; 1.2051x over previous
//
#include <hip/hip_runtime.h>

constexpr int H    = 128;
constexpr int LNUM = 5;
constexpr int NG   = 512;
constexpr int EMB  = 640;   // LNUM * H
constexpr float BN_EPS = 1e-5f;

typedef __attribute__((ext_vector_type(8))) short bf16x8;
typedef __attribute__((ext_vector_type(4))) float f32x4;

__device__ inline unsigned short f2bf(float f){
  unsigned u = __builtin_bit_cast(unsigned, f);
  u += 0x7FFF + ((u >> 16) & 1);
  return (unsigned short)(u >> 16);
}
__device__ inline float bf2f(unsigned short h){
  unsigned u = ((unsigned)h) << 16;
  return __builtin_bit_cast(float, u);
}

// bijective XCD chunk swizzle (m204)
__device__ inline int xcd_swz(int bid, int nwg){
  int q = nwg >> 3, r = nwg & 7;
  int xcd = bid & 7, idx = bid >> 3;
  return (xcd < r ? xcd*(q+1) : r*(q+1) + (xcd-r)*q) + idx;
}

// ---------------- utility ----------------
__global__ void k_zerof(float* p, int n){
  int i = blockIdx.x*256 + threadIdx.x;
  if (i < n) p[i] = 0.f;
}
__global__ void k_zeroi(int* p, int n){
  int i = blockIdx.x*256 + threadIdx.x;
  if (i < n) p[i] = 0;
}

// ---------------- CSR build ----------------
__global__ void k_hist(const int* __restrict__ dst, int E, int* deg){
  int e = blockIdx.x*256 + threadIdx.x;
  if (e < E) atomicAdd(&deg[dst[e]], 1);
}

// shfl-based block scan: degcur -> exclusive cursor, rowptr[i+1] = inclusive
__global__ __launch_bounds__(1024) void k_scan(int* degcur, int* __restrict__ rowptr, int n){
  __shared__ int wsum[16];
  __shared__ int carry;
  int tid = threadIdx.x, wid = tid >> 6, lane = tid & 63;
  if (tid == 0){ carry = 0; rowptr[0] = 0; }
  __syncthreads();
  for (int base = 0; base < n; base += 1024){
    int v = (base + tid < n) ? degcur[base + tid] : 0;
    int s = v;
#pragma unroll
    for (int off = 1; off < 64; off <<= 1){
      int t = __shfl_up(s, off);
      if (lane >= off) s += t;
    }
    if (lane == 63) wsum[wid] = s;
    __syncthreads();
    if (wid == 0 && lane < 16){
      int wv = wsum[lane];
#pragma unroll
      for (int off = 1; off < 16; off <<= 1){
        int t = __shfl_up(wv, off);
        if (lane >= off) wv += t;
      }
      wsum[lane] = wv;
    }
    __syncthreads();
    int incl = s + (wid ? wsum[wid-1] : 0) + carry;
    if (base + tid < n){ rowptr[base + tid + 1] = incl; degcur[base + tid] = incl - v; }
    __syncthreads();
    if (tid == 0) carry += wsum[15];
    __syncthreads();
  }
}

__global__ void k_scatter(const int* __restrict__ src, const int* __restrict__ dst,
                          int E, int* cursor, int* __restrict__ colsrc){
  int e = blockIdx.x*256 + threadIdx.x;
  if (e < E){
    int d = dst[e];
    int pos = atomicAdd(&cursor[d], 1);
    colsrc[pos] = src[e];
  }
}

__global__ void k_gstart(const int* __restrict__ batch, int N, int* __restrict__ gstart){
  int g = blockIdx.x*256 + threadIdx.x;
  if (g <= NG){
    int lo = 0, hi = N;
    while (lo < hi){
      int mid = (lo + hi) >> 1;
      if (batch[mid] < g) lo = mid + 1; else hi = mid;
    }
    gstart[g] = lo;
  }
}

// ---- weight cast+transpose: W[k][n] f32 -> Wt[n][ldt] bf16 at column offset koff ----
__global__ void k_castT(const float* __restrict__ W, unsigned short* __restrict__ Wt,
                        int K, int Nn, int ldt, int koff){
  __shared__ float sh[32][33];
  const size_t in_off  = (size_t)blockIdx.z * K * Nn;
  const size_t out_off = (size_t)blockIdx.z * Nn * ldt;
  int n0 = blockIdx.x*32, k0 = blockIdx.y*32;
  int tx = threadIdx.x, ty = threadIdx.y;   // 32 x 8
  for (int r = ty; r < 32; r += 8)
    sh[r][tx] = W[in_off + (size_t)(k0 + r)*Nn + n0 + tx];
  __syncthreads();
  for (int r = ty; r < 32; r += 8)
    Wt[out_off + (size_t)(n0 + r)*ldt + koff + k0 + tx] = f2bf(sh[tx][r]);
}

__global__ void k_bias2(const float* __restrict__ a, const float* __restrict__ b,
                        float* __restrict__ o){
  int i = threadIdx.x;
  o[i] = a[i] + b[i];
}

// ------- GIN aggregation: wave per node, lane handles 2 feats via u32 -------
// edge loop unrolled x4 so 4 gather rows are in flight
template<bool IN_BF16>
__global__ __launch_bounds__(256) void k_agg(const void* __restrict__ hin_, int ldh,
                                             const int* __restrict__ rowptr,
                                             const int* __restrict__ colsrc,
                                             const float* __restrict__ epsp,
                                             unsigned short* __restrict__ outp, int nN){
  int node = blockIdx.x*4 + (threadIdx.x >> 6);
  if (node >= nN) return;
  int lane = threadIdx.x & 63;
  float a0, a1;
  if (IN_BF16){
    unsigned u = ((const unsigned*)hin_)[((size_t)node*ldh >> 1) + lane];
    a0 = bf2f((unsigned short)u); a1 = bf2f((unsigned short)(u >> 16));
  } else {
    float2 f = ((const float2*)hin_)[((size_t)node*ldh >> 1) + lane];
    a0 = f.x; a1 = f.y;
  }
  float ep = 1.0f + *epsp;
  a0 *= ep; a1 *= ep;
  int e = rowptr[node], e1 = rowptr[node+1];
  const int ld2 = ldh >> 1;
  for (; e + 4 <= e1; e += 4){
    int s0 = colsrc[e], s1 = colsrc[e+1], s2 = colsrc[e+2], s3 = colsrc[e+3];
    if (IN_BF16){
      unsigned u0 = ((const unsigned*)hin_)[(size_t)s0*ld2 + lane];
      unsigned u1 = ((const unsigned*)hin_)[(size_t)s1*ld2 + lane];
      unsigned u2 = ((const unsigned*)hin_)[(size_t)s2*ld2 + lane];
      unsigned u3 = ((const unsigned*)hin_)[(size_t)s3*ld2 + lane];
      a0 += bf2f((unsigned short)u0) + bf2f((unsigned short)u1)
          + bf2f((unsigned short)u2) + bf2f((unsigned short)u3);
      a1 += bf2f((unsigned short)(u0 >> 16)) + bf2f((unsigned short)(u1 >> 16))
          + bf2f((unsigned short)(u2 >> 16)) + bf2f((unsigned short)(u3 >> 16));
    } else {
      float2 f0 = ((const float2*)hin_)[(size_t)s0*ld2 + lane];
      float2 f1 = ((const float2*)hin_)[(size_t)s1*ld2 + lane];
      float2 f2 = ((const float2*)hin_)[(size_t)s2*ld2 + lane];
      float2 f3 = ((const float2*)hin_)[(size_t)s3*ld2 + lane];
      a0 += f0.x + f1.x + f2.x + f3.x;
      a1 += f0.y + f1.y + f2.y + f3.y;
    }
  }
  for (; e < e1; ++e){
    int s = colsrc[e];
    if (IN_BF16){
      unsigned u = ((const unsigned*)hin_)[(size_t)s*ld2 + lane];
      a0 += bf2f((unsigned short)u); a1 += bf2f((unsigned short)(u >> 16));
    } else {
      float2 f = ((const float2*)hin_)[(size_t)s*ld2 + lane];
      a0 += f.x; a1 += f.y;
    }
  }
  ((unsigned*)outp)[((size_t)node*H >> 1) + lane] =
      (unsigned)f2bf(a0) | ((unsigned)f2bf(a1) << 16);
}

// ---------------- BN finalize ----------------
__global__ void k_bnfin(float* sums, float* sumsq,
                        const float* __restrict__ g, const float* __restrict__ b,
                        float* __restrict__ scale, float* __restrict__ shift, float invn){
  int c = threadIdx.x;
  float m = sums[c]*invn;
  float v = sumsq[c]*invn - m*m;
  float inv = rsqrtf(v + BN_EPS);
  float sc = g[c]*inv;
  scale[c] = sc;
  shift[c] = b[c] - m*sc;
  sums[c] = 0.f; sumsq[c] = 0.f;
}

// out[r][c] = bf16(relu(scale[c]*bf2f(U[r][c]) + shift[c])), out leading-dim ldo
__global__ __launch_bounds__(256) void k_bnapply(const unsigned short* __restrict__ U,
                                                 const float* __restrict__ scale,
                                                 const float* __restrict__ shift,
                                                 unsigned short* __restrict__ out,
                                                 int ldo, int n){
  int i = blockIdx.x*256 + threadIdx.x;
  int total = n * (H/4);
  if (i < total){
    int r = i >> 5;
    int c4 = (i & 31) << 2;
    uint2 up = *(const uint2*)(U + (size_t)r*H + c4);
    float4 sc = *(const float4*)(scale + c4);
    float4 sf = *(const float4*)(shift + c4);
    float a = fmaxf(fmaf(sc.x, bf2f((unsigned short)up.x),        sf.x), 0.f);
    float b = fmaxf(fmaf(sc.y, bf2f((unsigned short)(up.x>>16)),  sf.y), 0.f);
    float c = fmaxf(fmaf(sc.z, bf2f((unsigned short)up.y),        sf.z), 0.f);
    float d = fmaxf(fmaf(sc.w, bf2f((unsigned short)(up.y>>16)),  sf.w), 0.f);
    uint2 o;
    o.x = (unsigned)f2bf(a) | ((unsigned)f2bf(b) << 16);
    o.y = (unsigned)f2bf(c) | ((unsigned)f2bf(d) << 16);
    *(uint2*)(out + (size_t)r*ldo + c4) = o;
  }
}

// ---------------- pooling + prediction heads ----------------
__global__ __launch_bounds__(320) void k_pool(const unsigned short* __restrict__ xall,
                                              const int* __restrict__ gstart,
                                              float* __restrict__ pooled){
  int g = blockIdx.x;
  int t = threadIdx.x;
  int n0 = gstart[g], n1 = gstart[g+1];
  float a0 = 0.f, a1 = 0.f;
  for (int n = n0; n < n1; ++n){
    unsigned u = ((const unsigned*)xall)[(size_t)n*(EMB/2) + t];
    a0 += bf2f((unsigned short)u); a1 += bf2f((unsigned short)(u >> 16));
  }
  *(float2*)(pooled + (size_t)g*EMB + 2*t) = make_float2(a0, a1);
}

__global__ __launch_bounds__(128) void k_pred(const float* __restrict__ pooled,
                                              const float* __restrict__ W,
                                              const float* __restrict__ b,
                                              float* __restrict__ xcat){
  int g = blockIdx.x, l = blockIdx.y, o = threadIdx.x;
  __shared__ float sh[128];
  sh[o] = pooled[(size_t)g*EMB + l*H + o];
  __syncthreads();
  const float* Wl = W + (size_t)l*H*H;
  float acc = b[l*H + o];
  for (int k = 0; k < H; ++k) acc = fmaf(sh[k], Wl[k*H + o], acc);
  xcat[(size_t)g*EMB + l*H + o] = acc;
}

// ---------------- bf16 MFMA GEMM, 128x128 tile, BK=64, 8 waves (2x4) ----------------
// depth-2 pipeline, counted vmcnt(4); LDS-transpose coalesced epilogue.
// DUAL: A rows are [A | A2] concatenated along K (each K/2 wide).
template<bool RELU, bool OUT_BF16, bool DUAL>
__global__ __launch_bounds__(512) void k_mm(
    const unsigned short* __restrict__ A, int lda,
    const unsigned short* __restrict__ A2,
    const unsigned short* __restrict__ Bt, int ldb,
    const float* __restrict__ bias,
    void* __restrict__ Cv, int ldc,
    int M, int K)
{
  __shared__ union LdsU {
    unsigned short stage[2][2][128*64];   // [buf][A/B] 64 KB
    unsigned short sc16[128*136];         // 34 KB epilogue scratch (bf16)
    float          sc32[128*132];         // 66 KB epilogue scratch (f32)
  } u;
  const int tid  = threadIdx.x;
  const int lane = tid & 63;
  const int w    = tid >> 6;              // 0..7
  const int wr   = w >> 2, wc = w & 3;    // 2 x 4 wave grid

  const int nwg = gridDim.x * gridDim.y;
  const int bid = blockIdx.y * gridDim.x + blockIdx.x;
  const int wg  = xcd_swz(bid, nwg);
  const int col0 = (wg % gridDim.x) * 128;
  const int row0 = (wg / gridDim.x) * 128;
  const int KA   = DUAL ? (K >> 1) : K;

  // staging: wave w owns LDS bytes [w*2K, w*2K+2K) per array, 2 chunks of 1KB
  const unsigned short *sA[2], *sA2[2], *sB[2];
  int dOff[2];
#pragma unroll
  for (int j = 0; j < 2; ++j){
    int d = w*2048 + j*1024 + lane*16;        // linear LDS byte dest
    int m = d >> 7;                           // tile row of this dest
    int inner = (d & 127) ^ ((m & 7) << 4);   // inverse-swizzled byte-in-row
    int gm = row0 + m; if (gm > M-1) gm = M-1;
    sA[j]  = A  + (size_t)gm*lda + (inner >> 1);
    if (DUAL) sA2[j] = A2 + (size_t)gm*lda + (inner >> 1);
    sB[j]  = Bt + (size_t)(col0 + m)*ldb + (inner >> 1);
    dOff[j] = w*2048 + j*1024;
  }

  f32x4 acc[4][2];
#pragma unroll
  for (int i = 0; i < 4; ++i)
#pragma unroll
    for (int j = 0; j < 2; ++j)
      acc[i][j] = (f32x4){0.f, 0.f, 0.f, 0.f};

  auto STAGE = [&](int buf, int kt){            // 4 loads per wave
    int k0 = kt*64;
    int ka = k0;
    bool second = DUAL && (k0 >= KA);
    if (second) ka = k0 - KA;
#pragma unroll
    for (int j = 0; j < 2; ++j){
      const unsigned short* srcA = second ? (sA2[j] + ka) : (sA[j] + ka);
      __builtin_amdgcn_global_load_lds(
          (const __attribute__((address_space(1))) void*)srcA,
          (__attribute__((address_space(3))) void*)((char*)&u.stage[buf][0][0] + dOff[j]),
          16, 0, 0);
    }
#pragma unroll
    for (int j = 0; j < 2; ++j)
      __builtin_amdgcn_global_load_lds(
          (const __attribute__((address_space(1))) void*)(sB[j] + k0),
          (__attribute__((address_space(3))) void*)((char*)&u.stage[buf][1][0] + dOff[j]),
          16, 0, 0);
  };

  auto COMPUTE = [&](int buf){
    const char* Ab = (const char*)&u.stage[buf][0][0];
    const char* Bb = (const char*)&u.stage[buf][1][0];
#pragma unroll
    for (int kk = 0; kk < 2; ++kk){
      const int kb = kk*64 + ((lane >> 4) << 4);
      bf16x8 af[4], bfr[2];
#pragma unroll
      for (int i = 0; i < 4; ++i){
        int row = wr*64 + i*16 + (lane & 15);
        int ab  = (row*128 + kb) ^ ((row & 7) << 4);
        af[i] = *(const bf16x8*)(Ab + ab);
      }
#pragma unroll
      for (int j = 0; j < 2; ++j){
        int col = wc*32 + j*16 + (lane & 15);
        int bb  = (col*128 + kb) ^ ((col & 7) << 4);
        bfr[j] = *(const bf16x8*)(Bb + bb);
      }
#pragma unroll
      for (int i = 0; i < 4; ++i)
#pragma unroll
        for (int j = 0; j < 2; ++j)
          acc[i][j] = __builtin_amdgcn_mfma_f32_16x16x32_bf16(af[i], bfr[j], acc[i][j], 0, 0, 0);
    }
  };

  const int NT = K / 64;   // >= 2 for all uses
  STAGE(0, 0);
  STAGE(1, 1);
  asm volatile("s_waitcnt vmcnt(4)" ::: "memory");   // tile 0 landed
  __syncthreads();

  int cur = 0;
  for (int t = 0; t < NT; ++t){
    COMPUTE(cur);
    if (t == NT-1) break;
    __syncthreads();                                 // all waves done reading buf cur
    if (t + 2 < NT){
      STAGE(cur, t + 2);                             // 4 new loads
      asm volatile("s_waitcnt vmcnt(4)" ::: "memory"); // tile t+1 landed, t+2 in flight
    } else {
      asm volatile("s_waitcnt vmcnt(0)" ::: "memory"); // final tile landed
    }
    __syncthreads();
    cur ^= 1;
  }

  // ---- epilogue: transpose via LDS, coalesced stream-out ----
  __syncthreads();   // staging buffers now dead
  if (OUT_BF16){
#pragma unroll
    for (int j = 0; j < 2; ++j){
      int cl = wc*32 + j*16 + (lane & 15);
      float bs = bias[col0 + cl];
#pragma unroll
      for (int i = 0; i < 4; ++i){
        int rb = wr*64 + i*16 + ((lane >> 4) << 2);
#pragma unroll
        for (int r = 0; r < 4; ++r){
          float v = acc[i][j][r] + bs;
          if (RELU) v = fmaxf(v, 0.f);
          u.sc16[(rb + r)*136 + cl] = f2bf(v);
        }
      }
    }
    __syncthreads();
    unsigned short* Cb = (unsigned short*)Cv;
    for (int idx = tid; idx < 128*16; idx += 512){
      int rr = idx >> 4, seg = idx & 15;
      int grow = row0 + rr;
      if (grow < M){
        uint4 vv = *(const uint4*)&u.sc16[rr*136 + seg*8];
        *(uint4*)(Cb + (size_t)grow*ldc + col0 + seg*8) = vv;
      }
    }
  } else {
#pragma unroll
    for (int j = 0; j < 2; ++j){
      int cl = wc*32 + j*16 + (lane & 15);
      float bs = bias[col0 + cl];
#pragma unroll
      for (int i = 0; i < 4; ++i){
        int rb = wr*64 + i*16 + ((lane >> 4) << 2);
#pragma unroll
        for (int r = 0; r < 4; ++r){
          float v = acc[i][j][r] + bs;
          if (RELU) v = fmaxf(v, 0.f);
          u.sc32[(rb + r)*132 + cl] = v;
        }
      }
    }
    __syncthreads();
    float* Cf = (float*)Cv;
    for (int idx = tid; idx < 128*32; idx += 512){
      int rr = idx >> 5, seg = idx & 31;
      int grow = row0 + rr;
      if (grow < M){
        float4 vv = *(const float4*)&u.sc32[rr*132 + seg*4];
        *(float4*)(Cf + (size_t)grow*ldc + col0 + seg*4) = vv;
      }
    }
  }
}

// ------- conv GEMM: 128x128 tile, K=128 one-shot, 8 waves, fused pre-BN + stats -------
template<bool PRO_BN, bool STATS>
__global__ __launch_bounds__(512) void k_mmc(
    const unsigned short* __restrict__ A,     // [M][128] bf16
    const unsigned short* __restrict__ Bt,    // [128][128] bf16, n-major
    const float* __restrict__ bias,           // [128]
    const float* __restrict__ kscale, const float* __restrict__ kshift,
    unsigned short* __restrict__ C, int ldc,
    float* sums, float* sumsq,
    int M)
{
  __shared__ unsigned short shm[2*128*128];   // 64 KB: As | Bs; epilogue reuses as [128][136]
  unsigned short* As = shm;
  unsigned short* Bs = shm + 128*128;
  const int tid  = threadIdx.x;
  const int lane = tid & 63;
  const int w    = tid >> 6;              // 0..7
  const int wr   = w >> 2, wc = w & 3;

  const int wg   = xcd_swz(blockIdx.x, gridDim.x);
  const int row0 = wg * 128;

  // stage whole tiles: wave w owns 4 KB of each array (4 chunks of 1 KB)
#pragma unroll
  for (int j = 0; j < 4; ++j){
    int d = w*4096 + j*1024 + lane*16;
    int m = d >> 8;                            // row (256 B rows)
    int inner = (d & 255) ^ ((m & 15) << 4);   // inverse swizzle
    int gm = row0 + m; if (gm > M-1) gm = M-1;
    __builtin_amdgcn_global_load_lds(
        (const __attribute__((address_space(1))) void*)(A + (size_t)gm*H + (inner >> 1)),
        (__attribute__((address_space(3))) void*)((char*)As + w*4096 + j*1024),
        16, 0, 0);
    __builtin_amdgcn_global_load_lds(
        (const __attribute__((address_space(1))) void*)(Bt + (size_t)m*H + (inner >> 1)),
        (__attribute__((address_space(3))) void*)((char*)Bs + w*4096 + j*1024),
        16, 0, 0);
  }
  asm volatile("s_waitcnt vmcnt(0)" ::: "memory");
  __syncthreads();

  f32x4 acc[4][2];
#pragma unroll
  for (int i = 0; i < 4; ++i)
#pragma unroll
    for (int j = 0; j < 2; ++j)
      acc[i][j] = (f32x4){0.f, 0.f, 0.f, 0.f};

#pragma unroll
  for (int kk = 0; kk < 4; ++kk){
    const int kb = kk*64 + ((lane >> 4) << 4);
    bf16x8 af[4], bfr[2];
#pragma unroll
    for (int i = 0; i < 4; ++i){
      int row = wr*64 + i*16 + (lane & 15);
      int ab  = (row*256 + kb) ^ ((row & 15) << 4);
      af[i] = *(const bf16x8*)((const char*)As + ab);
    }
#pragma unroll
    for (int j = 0; j < 2; ++j){
      int col = wc*32 + j*16 + (lane & 15);
      int bb  = (col*256 + kb) ^ ((col & 15) << 4);
      bfr[j] = *(const bf16x8*)((const char*)Bs + bb);
    }
    if (PRO_BN){
      int k8 = kk*32 + ((lane >> 4) << 3);
      float4 s0 = *(const float4*)(kscale + k8), s1 = *(const float4*)(kscale + k8 + 4);
      float4 f0 = *(const float4*)(kshift + k8), f1 = *(const float4*)(kshift + k8 + 4);
      float sc[8] = {s0.x,s0.y,s0.z,s0.w,s1.x,s1.y,s1.z,s1.w};
      float sf[8] = {f0.x,f0.y,f0.z,f0.w,f1.x,f1.y,f1.z,f1.w};
#pragma unroll
      for (int i = 0; i < 4; ++i){
        bf16x8 a = af[i], o;
#pragma unroll
        for (int jj = 0; jj < 8; ++jj){
          float v = fmaxf(fmaf(sc[jj], bf2f((unsigned short)a[jj]), sf[jj]), 0.f);
          o[jj] = (short)f2bf(v);
        }
        af[i] = o;
      }
    }
#pragma unroll
    for (int i = 0; i < 4; ++i)
#pragma unroll
      for (int j = 0; j < 2; ++j)
        acc[i][j] = __builtin_amdgcn_mfma_f32_16x16x32_bf16(af[i], bfr[j], acc[i][j], 0, 0, 0);
  }

  if (STATS){
#pragma unroll
    for (int j = 0; j < 2; ++j){
      int col = wc*32 + j*16 + (lane & 15);
      float bs = bias[col];
      float s = 0.f, q = 0.f;
#pragma unroll
      for (int i = 0; i < 4; ++i){
        int rb = row0 + wr*64 + i*16 + ((lane >> 4) << 2);
#pragma unroll
        for (int r = 0; r < 4; ++r){
          if (rb + r < M){
            float v = acc[i][j][r] + bs;
            s += v; q += v*v;
          }
        }
      }
      s += __shfl_xor(s, 16); q += __shfl_xor(q, 16);
      s += __shfl_xor(s, 32); q += __shfl_xor(q, 32);
      if (lane < 16){
        atomicAdd(&sums[col], s);
        atomicAdd(&sumsq[col], q);
      }
    }
  }

  // epilogue: transpose via LDS (staging dead), coalesced 16-B stores
  __syncthreads();
#pragma unroll
  for (int j = 0; j < 2; ++j){
    int cl = wc*32 + j*16 + (lane & 15);
    float bs = bias[cl];
#pragma unroll
    for (int i = 0; i < 4; ++i){
      int rb = wr*64 + i*16 + ((lane >> 4) << 2);
#pragma unroll
      for (int r = 0; r < 4; ++r)
        shm[(rb + r)*136 + cl] = f2bf(acc[i][j][r] + bs);
    }
  }
  __syncthreads();
  for (int idx = tid; idx < 128*16; idx += 512){
    int rr = idx >> 4, seg = idx & 15;
    int grow = row0 + rr;
    if (grow < M){
      uint4 vv = *(const uint4*)&shm[rr*136 + seg*8];
      *(uint4*)(C + (size_t)grow*ldc + seg*8) = vv;
    }
  }
}

// ---------------- f32 GEMM 64x64 (graph FF, M=512) ----------------
template<bool RELU, bool ADD_D>
__global__ __launch_bounds__(256) void k_gemm64(
    const float* __restrict__ A, int lda,
    const float* __restrict__ B, int ldb,
    const float* __restrict__ bias,
    const float* D, int ldd,
    float* C, int ldc,
    int M, int N, int K)
{
  __shared__ float As[32][68];
  __shared__ float Bs[32][64];
  const int tid  = threadIdx.x;
  const int tx   = tid & 15;
  const int ty   = tid >> 4;
  const int row0 = blockIdx.x * 64;
  const int col0 = blockIdx.y * 64;
  const int am = tid >> 3;
  const int ak = (tid & 7) << 2;
  const int bk = tid >> 4;
  const int bn = (tid & 15) << 2;
  float acc[4][4] = {};

  for (int k0 = 0; k0 < K; k0 += 32){
#pragma unroll
    for (int h = 0; h < 2; ++h){
      int m  = am + h*32;
      int gr = row0 + m;
      float4 v = make_float4(0.f, 0.f, 0.f, 0.f);
      if (gr < M) v = *(const float4*)(A + (size_t)gr*lda + k0 + ak);
      As[ak+0][m]=v.x; As[ak+1][m]=v.y; As[ak+2][m]=v.z; As[ak+3][m]=v.w;
    }
#pragma unroll
    for (int h = 0; h < 2; ++h){
      int kk = bk + h*16;
      *(float4*)(&Bs[kk][bn]) = *(const float4*)(B + (size_t)(k0+kk)*ldb + col0 + bn);
    }
    __syncthreads();
#pragma unroll 8
    for (int k = 0; k < 32; ++k){
      float4 a = *(const float4*)(&As[k][ty<<2]);
      float4 b = *(const float4*)(&Bs[k][tx<<2]);
      float av[4] = {a.x,a.y,a.z,a.w};
      float bv[4] = {b.x,b.y,b.z,b.w};
#pragma unroll
      for (int i = 0; i < 4; ++i)
#pragma unroll
        for (int j = 0; j < 4; ++j)
          acc[i][j] = fmaf(av[i], bv[j], acc[i][j]);
    }
    __syncthreads();
  }

  const int col = col0 + (tx<<2);
  float4 bv = *(const float4*)(bias + col);
#pragma unroll
  for (int i = 0; i < 4; ++i){
    int row = row0 + (ty<<2) + i;
    if (row < M){
      float r[4] = {acc[i][0]+bv.x, acc[i][1]+bv.y, acc[i][2]+bv.z, acc[i][3]+bv.w};
      if (RELU){
#pragma unroll
        for (int j = 0; j < 4; ++j) r[j] = fmaxf(r[j], 0.f);
      }
      if (ADD_D){
        float4 d = *(const float4*)(D + (size_t)row*ldd + col);
        r[0]+=d.x; r[1]+=d.y; r[2]+=d.z; r[3]+=d.w;
      }
      *(float4*)(C + (size_t)row*ldc + col) = make_float4(r[0],r[1],r[2],r[3]);
    }
  }
}

// ---------------- host ----------------
extern "C" void kernel_launch(void* const* d_in, const int* in_sizes, int n_in,
                              void* d_out, int out_size, void* d_ws, size_t ws_size,
                              hipStream_t stream) {
  const float* x        = (const float*)d_in[0];
  const int*   ei       = (const int*)d_in[1];
  const int*   batch    = (const int*)d_in[2];
  const float* conv_W1  = (const float*)d_in[3];
  const float* conv_b1  = (const float*)d_in[4];
  const float* conv_g1  = (const float*)d_in[5];
  const float* conv_be1 = (const float*)d_in[6];
  const float* conv_W2  = (const float*)d_in[7];
  const float* conv_b2  = (const float*)d_in[8];
  const float* epsv     = (const float*)d_in[9];
  const float* bn_g     = (const float*)d_in[10];
  const float* bn_b     = (const float*)d_in[11];
  const float* pred_W   = (const float*)d_in[12];
  const float* pred_b   = (const float*)d_in[13];
  const float* gW       = (const float*)d_in[14];
  const float* gb       = (const float*)d_in[15];
  const float* gsW      = (const float*)d_in[16];
  const float* gsb      = (const float*)d_in[17];
  const float* lW       = (const float*)d_in[18];
  const float* lb       = (const float*)d_in[19];
  const float* lsW      = (const float*)d_in[20];
  const float* lsb      = (const float*)d_in[21];

  const int N = in_sizes[0] / H;
  const int E = in_sizes[1] / 2;
  const int* srcI = ei;
  const int* dstI = ei + E;

  float* out = (float*)d_out;
  float* GE = out;                              // [NG][EMB]
  float* NE = out + (size_t)NG*EMB;             // [N][EMB] f32
  float* XC = NE + (size_t)N*EMB;               // [NG][EMB]

  // ---- workspace layout ----
  unsigned short* xall = (unsigned short*)d_ws;             // [N][EMB] bf16
  unsigned short* h1   = xall + (size_t)N*EMB;              // [N][EMB] bf16
  unsigned short* h2   = h1 + (size_t)N*EMB;                // [N][EMB] bf16
  // conv-loop aliases inside h1 region (3*N*H < N*EMB)
  unsigned short* hpre = h1;                                // [N][H]
  unsigned short* ub   = h1 + (size_t)N*H;                  // [N][H]
  unsigned short* tb   = h1 + (size_t)2*N*H;                // [N][H]

  float* pooled  = (float*)(h2 + (size_t)N*EMB);            // [NG][EMB]
  float* gtmp1   = pooled + (size_t)NG*EMB;
  float* gtmp2   = gtmp1 + (size_t)NG*EMB;
  float* sums    = gtmp2 + (size_t)NG*EMB;                  // [128]
  float* sumsq   = sums + 128;
  float* bnscale = sumsq + 128;
  float* bnshift = bnscale + 128;
  float* biasNE  = bnshift + 128;                           // [640]
  unsigned short* W1t   = (unsigned short*)(biasNE + EMB);  // [L][H][H]
  unsigned short* W2t   = W1t + (size_t)LNUM*H*H;
  unsigned short* lWt01 = W2t + (size_t)LNUM*H*H;           // [2][EMB][EMB]
  unsigned short* Wcat  = lWt01 + (size_t)2*EMB*EMB;        // [EMB][2*EMB]
  int* rowptr = (int*)(Wcat + (size_t)2*EMB*EMB);           // [N+1]
  int* cursor = rowptr + (N + 1);                           // [N]
  int* colsrc = cursor + N;                                 // [E]
  int* gstart = colsrc + E;                                 // [NG+1]

  // stat accumulators must be zero every call
  k_zerof<<<1, 256, 0, stream>>>(sums, 256);

  // CSR build
  k_zeroi<<<(N+255)/256, 256, 0, stream>>>(cursor, N);
  k_hist<<<(E+255)/256, 256, 0, stream>>>(dstI, E, cursor);
  k_scan<<<1, 1024, 0, stream>>>(cursor, rowptr, N);
  k_scatter<<<(E+255)/256, 256, 0, stream>>>(srcI, dstI, E, cursor, colsrc);
  k_gstart<<<(NG+256)/256, 256, 0, stream>>>(batch, N, gstart);

  // weights -> bf16 transposed [n][k]
  const dim3 tb32(32, 8);
  k_castT<<<dim3(H/32, H/32, LNUM), tb32, 0, stream>>>(conv_W1, W1t, H, H, H, 0);
  k_castT<<<dim3(H/32, H/32, LNUM), tb32, 0, stream>>>(conv_W2, W2t, H, H, H, 0);
  k_castT<<<dim3(EMB/32, EMB/32, 2), tb32, 0, stream>>>(lW, lWt01, EMB, EMB, EMB, 0);
  k_castT<<<dim3(EMB/32, EMB/32, 1), tb32, 0, stream>>>(lW + (size_t)2*EMB*EMB, Wcat,
                                                        EMB, EMB, 2*EMB, 0);
  k_castT<<<dim3(EMB/32, EMB/32, 1), tb32, 0, stream>>>(lsW, Wcat, EMB, EMB, 2*EMB, EMB);
  k_bias2<<<1, EMB, 0, stream>>>(lb + (size_t)2*EMB, lsb, biasNE);

  const float invn = 1.0f / (float)N;
  const int nrow = (N + 127)/128;               // 391

  for (int l = 0; l < LNUM; ++l){
    if (l == 0)
      k_agg<false><<<(N+3)/4, 256, 0, stream>>>(x, H, rowptr, colsrc, epsv, hpre, N);
    else
      k_agg<true><<<(N+3)/4, 256, 0, stream>>>(xall + (size_t)(l-1)*H, EMB, rowptr, colsrc,
                                               epsv + l, hpre, N);

    // u = hpre @ W1 + b1  (bf16 out + stats)
    k_mmc<false,true><<<nrow, 512, 0, stream>>>(
        hpre, W1t + (size_t)l*H*H, conv_b1 + l*H, nullptr, nullptr,
        ub, H, sums, sumsq, N);
    k_bnfin<<<1, 128, 0, stream>>>(sums, sumsq, conv_g1 + l*H, conv_be1 + l*H,
                                   bnscale, bnshift, invn);
    // u2 = relu(bn1(u)) @ W2 + b2  (fused pre-BN on A; bf16 out + stats)
    k_mmc<true,true><<<nrow, 512, 0, stream>>>(
        ub, W2t + (size_t)l*H*H, conv_b2 + l*H, bnscale, bnshift,
        tb, H, sums, sumsq, N);
    k_bnfin<<<1, 128, 0, stream>>>(sums, sumsq, bn_g + l*H, bn_b + l*H,
                                   bnscale, bnshift, invn);
    k_bnapply<<<(N*32 + 255)/256, 256, 0, stream>>>(tb, bnscale, bnshift,
                                                    xall + (size_t)l*H, EMB, N);
  }

  // pooling + per-layer prediction heads -> xcat
  k_pool<<<NG, 320, 0, stream>>>(xall, gstart, pooled);
  k_pred<<<dim3(NG, LNUM), 128, 0, stream>>>(pooled, pred_W, pred_b, XC);

  // graph FF (f32, M=512): GE = relu-chain(XC) + XC @ gsW + gsb
  const dim3 gg((NG + 63)/64, EMB/64);
  k_gemm64<false,false><<<gg, 256, 0, stream>>>(XC, EMB, gsW, EMB, gsb,
                                                nullptr, 0, GE, EMB, NG, EMB, EMB);
  k_gemm64<true,false><<<gg, 256, 0, stream>>>(XC, EMB, gW, EMB, gb,
                                               nullptr, 0, gtmp1, EMB, NG, EMB, EMB);
  k_gemm64<true,false><<<gg, 256, 0, stream>>>(gtmp1, EMB, gW + (size_t)EMB*EMB, EMB, gb + EMB,
                                               nullptr, 0, gtmp2, EMB, NG, EMB, EMB);
  k_gemm64<true,true><<<gg, 256, 0, stream>>>(gtmp2, EMB, gW + (size_t)2*EMB*EMB, EMB, gb + 2*EMB,
                                              GE, EMB, GE, EMB, NG, EMB, EMB);

  // node FF (bf16 MFMA, col-fast grid + XCD swizzle):
  const dim3 gn(EMB/128, nrow);                 // (5, 391)
  // h1 = relu(xall @ lW0 + lb0)
  k_mm<true,true,false><<<gn, 512, 0, stream>>>(
      xall, EMB, nullptr, lWt01, EMB, lb, h1, EMB, N, EMB);
  // h2 = relu(h1 @ lW1 + lb1)
  k_mm<true,true,false><<<gn, 512, 0, stream>>>(
      h1, EMB, nullptr, lWt01 + (size_t)EMB*EMB, EMB, lb + EMB, h2, EMB, N, EMB);
  // NE = [h2 | xall] @ [lW2 ; lsW] + (lb2 + lsb)   (dual-A, K=1280, f32 out)
  k_mm<false,false,true><<<gn, 512, 0, stream>>>(
      h2, EMB, xall, Wcat, 2*EMB, biasNE, NE, EMB, N, 2*EMB);
}